// Round 1
// baseline (1224.569 us; speedup 1.0000x reference)
//
#include <hip/hip_runtime.h>
#include <hip/hip_bf16.h>

// GraphSAGE forward: proj -> [aggr -> gemm] x2 (+cls fused into gemm2)
// N=200000, E=3200000, IN_DIM=165, HID=64. All fp32.
//
// R9 design notes:
//  - CSR build rebuilt (post-mortem R8: NT loads did NOT stop csr write
//    amplification -- scatter WRITE stayed 157MB; the 8x-sharded re-read of
//    dst (100MB FETCH/pass x2 kernels) is also pure waste). New scheme:
//    (A) bucket_kernel: ONE pass over src/dst, partitions edges into NR=8
//        dst-range buckets (planes p_src/p_dst) with deterministic positions
//        via in-block prefix scans (no per-edge global atomics). 25.6MB read,
//        25.6MB dense writes.
//    (B1) bdeg: per-bucket degree count -- counts slice (100KB) XCD-local.
//    (B2) bscatter: per-bucket scatter -- csr slice (1.6MB) + cursor (100KB)
//        XCD-local, streams only 3.2MB/XCD so dirty csr lines accumulate.
//    Bucket planes alias the aggr buffer (dead until after scatter).
//  - proj/gemm: register double-buffered staging (issue kc+1 global loads
//    before computing kc) -- R8 counters showed proj at 1.07TB/s read, 29%
//    VALU: staging latency was fully exposed per phase.
//  - matmuls: 256-node x 64-out blocks, 8x8 micro-tile, transposed x_s.
//  - cls fused into gemm2.

#define NNODES 200000
#define NEDGES 3200000
#define INDIM 165
#define HID 64

#define NR 8
#define RSIZE (NNODES / NR)   // 25000
#define CAP 416000            // per-bucket capacity (~400k expected, 26 sigma slack)
#define ACHUNK 4096

#define SCAN_T 256
#define SCAN_I 8
#define SCAN_CHUNK (SCAN_T * SCAN_I)

#define BKP 15            // proj K chunk: 165 = 11*15
#define BKG 16            // gemm K chunk: 64 = 4*16
#define XT_STRIDE 260     // >=256 nodes, %4==0 (f4 aligned)

typedef float f4 __attribute__((ext_vector_type(4)));

#define RELU4(v) { v.x=fmaxf(v.x,0.f); v.y=fmaxf(v.y,0.f); v.z=fmaxf(v.z,0.f); v.w=fmaxf(v.w,0.f); }

#define MT_FMA(xv0, xv1, wv0, wv1) \
  accA[0] += xv0.x * wv0; accB[0] += xv0.x * wv1; \
  accA[1] += xv0.y * wv0; accB[1] += xv0.y * wv1; \
  accA[2] += xv0.z * wv0; accB[2] += xv0.z * wv1; \
  accA[3] += xv0.w * wv0; accB[3] += xv0.w * wv1; \
  accA[4] += xv1.x * wv0; accB[4] += xv1.x * wv1; \
  accA[5] += xv1.y * wv0; accB[5] += xv1.y * wv1; \
  accA[6] += xv1.z * wv0; accB[6] += xv1.z * wv1; \
  accA[7] += xv1.w * wv0; accB[7] += xv1.w * wv1;

// ---------------- proj: h = relu(x @ Wp + bp) -----------------------------
__global__ __launch_bounds__(256, 3)
void proj_kernel(const float* __restrict__ x,
                 const float* __restrict__ Wp,
                 const float* __restrict__ bp,
                 float* __restrict__ h, int n) {
  __shared__ float x_s[BKP * XT_STRIDE];
  __shared__ float w_s[BKP * HID];
  int t = threadIdx.x;
  int tx = t & 7;
  int ng = t >> 3;
  int n0 = blockIdx.x * 256;

  f4 b0 = ((const f4*)bp)[tx * 2];
  f4 b1 = ((const f4*)bp)[tx * 2 + 1];
  f4 accA[8], accB[8];
  #pragma unroll
  for (int i = 0; i < 8; ++i) { accA[i] = b0; accB[i] = b1; }

  // prefetch kc=0 into registers
  float xr[BKP];
  f4 wpr;
  #pragma unroll
  for (int j = 0; j < BKP; ++j) {
    int i = t + j * 256;
    int node = i / BKP, col = i - node * BKP;
    int gi = n0 + node; if (gi >= n) gi = n - 1;
    xr[j] = x[(size_t)gi * INDIM + col];
  }
  if (t < BKP * HID / 4) wpr = ((const f4*)Wp)[t];

  for (int kc = 0; kc < INDIM / BKP; ++kc) {
    if (kc) __syncthreads();
    #pragma unroll
    for (int j = 0; j < BKP; ++j) {
      int i = t + j * 256;
      int node = i / BKP, col = i - node * BKP;
      x_s[col * XT_STRIDE + node] = xr[j];
    }
    if (t < BKP * HID / 4) ((f4*)w_s)[t] = wpr;
    __syncthreads();
    if (kc + 1 < INDIM / BKP) {
      #pragma unroll
      for (int j = 0; j < BKP; ++j) {
        int i = t + j * 256;
        int node = i / BKP, col = i - node * BKP;
        int gi = n0 + node; if (gi >= n) gi = n - 1;
        xr[j] = x[(size_t)gi * INDIM + (kc + 1) * BKP + col];
      }
      if (t < BKP * HID / 4) wpr = ((const f4*)(Wp + (kc + 1) * BKP * HID))[t];
    }
    #pragma unroll
    for (int k = 0; k < BKP; ++k) {
      const float* xrp = &x_s[k * XT_STRIDE + ng * 8];
      f4 xv0 = *(const f4*)xrp;
      f4 xv1 = *(const f4*)(xrp + 4);
      f4 wv0 = *(const f4*)&w_s[k * HID + tx * 8];
      f4 wv1 = *(const f4*)&w_s[k * HID + tx * 8 + 4];
      MT_FMA(xv0, xv1, wv0, wv1)
    }
  }
  #pragma unroll
  for (int i = 0; i < 8; ++i) {
    int node = n0 + ng * 8 + i;
    if (node < n) {
      f4 a = accA[i], b = accB[i];
      RELU4(a) RELU4(b)
      *(f4*)&h[(size_t)node * HID + tx * 8] = a;
      *(f4*)&h[(size_t)node * HID + tx * 8 + 4] = b;
    }
  }
}

// ---------------- phase A: bucket edges by dst range ----------------------
// One pass over src/dst. Deterministic in-bucket positions: per-thread
// histogram -> wave inclusive scans (shfl_up) -> cross-wave prefix -> one
// global atomicAdd per (block,bucket) reserving a dense window.
__global__ __launch_bounds__(256)
void bucket_kernel(const int* __restrict__ src, const int* __restrict__ dst,
                   int* __restrict__ gbase,
                   int* __restrict__ p_src, int* __restrict__ p_dst, int e) {
  __shared__ int wpart[4][NR];
  __shared__ int wbase[4][NR];
  __shared__ int bbase[NR];
  __shared__ int posm[NR][256];
  int t = threadIdx.x;
  int lane = t & 63, wid = t >> 6;
  int base = blockIdx.x * ACHUNK;

  int dreg[16];
  int c[NR];
  #pragma unroll
  for (int r = 0; r < NR; ++r) c[r] = 0;
  #pragma unroll
  for (int j = 0; j < 16; ++j) {
    int i = base + t + j * 256;
    int d = (i < e) ? __builtin_nontemporal_load(&dst[i]) : -1;
    dreg[j] = d;
    if (d >= 0) c[d / RSIZE]++;
  }
  // wave-level inclusive scans, one per bucket
  int excl[NR];
  #pragma unroll
  for (int r = 0; r < NR; ++r) {
    int v = c[r];
    int incl = v;
    #pragma unroll
    for (int off = 1; off < 64; off <<= 1) {
      int y = __shfl_up(incl, off, 64);
      if (lane >= off) incl += y;
    }
    excl[r] = incl - v;
    if (lane == 63) wpart[wid][r] = incl;
  }
  __syncthreads();
  if (t < NR) {
    int s0 = wpart[0][t], s1 = wpart[1][t], s2 = wpart[2][t], s3 = wpart[3][t];
    int tot = s0 + s1 + s2 + s3;
    bbase[t] = atomicAdd(&gbase[t], tot);
    wbase[0][t] = 0; wbase[1][t] = s0; wbase[2][t] = s0 + s1; wbase[3][t] = s0 + s1 + s2;
  }
  __syncthreads();
  #pragma unroll
  for (int r = 0; r < NR; ++r)
    posm[r][t] = r * CAP + bbase[r] + wbase[wid][r] + excl[r];
  #pragma unroll
  for (int j = 0; j < 16; ++j) {
    int d = dreg[j];
    if (d >= 0) {
      int s = __builtin_nontemporal_load(&src[base + t + j * 256]);
      int r = d / RSIZE;
      int p = posm[r][t]++;          // LDS, bank-conflict-free (addr = r*256+t)
      p_dst[p] = d;
      p_src[p] = s;
    }
  }
}

// ---------------- phase B1: per-bucket degree histogram -------------------
__global__ void bdeg_kernel(const int* __restrict__ gbase,
                            const int* __restrict__ p_dst,
                            int* __restrict__ counts) {
  int r = blockIdx.x & (NR - 1);
  int chunk = blockIdx.x >> 3;
  int n_r = gbase[r];
  int base = chunk * ACHUNK;
  if (base >= n_r) return;
  int end = min(base + ACHUNK, n_r);
  const int* pd = p_dst + (size_t)r * CAP;
  for (int i = base + (int)threadIdx.x; i < end; i += 256) {
    int d = __builtin_nontemporal_load(&pd[i]);
    atomicAdd(&counts[d], 1);
  }
}

// ---------------- scan ----------------------------------------------------
__global__ void scan1_kernel(const int* __restrict__ counts, int* __restrict__ row_ptr,
                             int* __restrict__ bsums, int n) {
  __shared__ int lds[SCAN_T];
  int b = blockIdx.x, t = threadIdx.x;
  int base = b * SCAN_CHUNK + t * SCAN_I;
  int v[SCAN_I];
  int s = 0;
  #pragma unroll
  for (int i = 0; i < SCAN_I; ++i) {
    int idx = base + i;
    v[i] = (idx < n) ? counts[idx] : 0;
    s += v[i];
  }
  lds[t] = s;
  __syncthreads();
  for (int off = 1; off < SCAN_T; off <<= 1) {
    int y = (t >= off) ? lds[t - off] : 0;
    __syncthreads();
    lds[t] += y;
    __syncthreads();
  }
  int incl = lds[t];
  int run = incl - s;
  #pragma unroll
  for (int i = 0; i < SCAN_I; ++i) {
    int idx = base + i;
    if (idx < n) row_ptr[idx] = run;
    run += v[i];
  }
  if (t == SCAN_T - 1) bsums[b] = incl;
}

__global__ void scan2_kernel(int* __restrict__ bsums, int nb) {
  __shared__ int lds[SCAN_T];
  int t = threadIdx.x;
  int v = (t < nb) ? bsums[t] : 0;
  lds[t] = v;
  __syncthreads();
  for (int off = 1; off < SCAN_T; off <<= 1) {
    int y = (t >= off) ? lds[t - off] : 0;
    __syncthreads();
    lds[t] += y;
    __syncthreads();
  }
  if (t < nb) bsums[t] = lds[t] - v;
}

__global__ void scan3_kernel(int* __restrict__ row_ptr, const int* __restrict__ bsums,
                             int* __restrict__ cursor, int n, int e) {
  int i = blockIdx.x * blockDim.x + threadIdx.x;
  if (i < n) {
    int v = row_ptr[i] + bsums[i / SCAN_CHUNK];
    row_ptr[i] = v;
    cursor[i] = v;
  }
  if (i == n) row_ptr[n] = e;
}

// ---------------- phase B2: per-bucket scatter into CSR -------------------
__global__ void bscatter_kernel(const int* __restrict__ gbase,
                                const int* __restrict__ p_src,
                                const int* __restrict__ p_dst,
                                int* __restrict__ cursor, int* __restrict__ csr_src) {
  int r = blockIdx.x & (NR - 1);
  int chunk = blockIdx.x >> 3;
  int n_r = gbase[r];
  int base = chunk * ACHUNK;
  if (base >= n_r) return;
  int end = min(base + ACHUNK, n_r);
  const int* pd = p_dst + (size_t)r * CAP;
  const int* ps = p_src + (size_t)r * CAP;
  for (int i = base + (int)threadIdx.x; i < end; i += 256) {
    int d = __builtin_nontemporal_load(&pd[i]);
    int s = __builtin_nontemporal_load(&ps[i]);
    int pos = atomicAdd(&cursor[d], 1);
    csr_src[pos] = s;
  }
}

// ---------------- mean aggregation (pull, CSR) ----------------------------
__global__ void aggr_kernel(const float* __restrict__ hin,
                            const int* __restrict__ row_ptr,
                            const int* __restrict__ csr_src,
                            float* __restrict__ aggr, int n) {
  int lane = threadIdx.x & 63;
  int grp = lane >> 4, sub = lane & 15;
  int node = (blockIdx.x * blockDim.x + threadIdx.x) >> 6;
  if (node >= n) return;
  int r0 = row_ptr[node], r1 = row_ptr[node + 1];
  f4 acc0 = {0.f, 0.f, 0.f, 0.f}, acc1 = {0.f, 0.f, 0.f, 0.f};
  int p = r0;
  for (; p + 8 <= r1; p += 8) {
    int i0 = csr_src[p + grp];
    int i1 = csr_src[p + 4 + grp];
    f4 v0 = *((const f4*)(hin + (size_t)i0 * HID) + sub);
    f4 v1 = *((const f4*)(hin + (size_t)i1 * HID) + sub);
    acc0 += v0;
    acc1 += v1;
  }
  if (p + 4 <= r1) {
    int i0 = csr_src[p + grp];
    acc0 += *((const f4*)(hin + (size_t)i0 * HID) + sub);
    p += 4;
  }
  int rem = r1 - p;
  if (grp < rem) {
    int i0 = csr_src[p + grp];
    acc1 += *((const f4*)(hin + (size_t)i0 * HID) + sub);
  }
  acc0 += acc1;
  #pragma unroll
  for (int c = 0; c < 4; ++c) {
    float v = acc0[c];
    v += __shfl_xor(v, 16, 64);
    v += __shfl_xor(v, 32, 64);
    acc0[c] = v;
  }
  int deg = r1 - r0;
  float rdeg = 1.f / (float)(deg > 1 ? deg : 1);
  if (grp == 0) {
    f4 o = acc0 * rdeg;
    *((f4*)(aggr + (size_t)node * HID) + sub) = o;
  }
}

// ---------------- gemm: hout = relu(aggr@Wl + bl + hin@Wr) ---------------
// register double-buffered staging
#define GEMM_BODY(aggrp, hinp) \
  { \
    float arg[BKG], hrg[BKG]; \
    f4 wlr, wrr; \
    _Pragma("unroll") \
    for (int j = 0; j < BKG; ++j) { \
      int i = t + j * 256; \
      int node = i >> 4, k = i & 15; \
      int gi = n0 + node; if (gi >= n) gi = n - 1; \
      arg[j] = aggrp[(size_t)gi * HID + k]; \
      hrg[j] = hinp[(size_t)gi * HID + k]; \
    } \
    wlr = ((const f4*)Wl)[t]; \
    wrr = ((const f4*)Wr)[t]; \
    for (int kc = 0; kc < HID / BKG; ++kc) { \
      if (kc) __syncthreads(); \
      _Pragma("unroll") \
      for (int j = 0; j < BKG; ++j) { \
        int i = t + j * 256; \
        int node = i >> 4, k = i & 15; \
        a_s[k * XT_STRIDE + node] = arg[j]; \
        h_s[k * XT_STRIDE + node] = hrg[j]; \
      } \
      ((f4*)wl_s)[t] = wlr; \
      ((f4*)wr_s)[t] = wrr; \
      __syncthreads(); \
      if (kc + 1 < HID / BKG) { \
        _Pragma("unroll") \
        for (int j = 0; j < BKG; ++j) { \
          int i = t + j * 256; \
          int node = i >> 4, k = i & 15; \
          int gi = n0 + node; if (gi >= n) gi = n - 1; \
          arg[j] = aggrp[(size_t)gi * HID + (kc + 1) * BKG + k]; \
          hrg[j] = hinp[(size_t)gi * HID + (kc + 1) * BKG + k]; \
        } \
        wlr = ((const f4*)(Wl + (kc + 1) * BKG * HID))[t]; \
        wrr = ((const f4*)(Wr + (kc + 1) * BKG * HID))[t]; \
      } \
      _Pragma("unroll") \
      for (int k = 0; k < BKG; ++k) { \
        const float* ar = &a_s[k * XT_STRIDE + ng * 8]; \
        const float* hr = &h_s[k * XT_STRIDE + ng * 8]; \
        f4 av0 = *(const f4*)ar; \
        f4 av1 = *(const f4*)(ar + 4); \
        f4 hv0 = *(const f4*)hr; \
        f4 hv1 = *(const f4*)(hr + 4); \
        f4 wl0 = *(const f4*)&wl_s[k * HID + tx * 8]; \
        f4 wl1 = *(const f4*)&wl_s[k * HID + tx * 8 + 4]; \
        f4 wr0 = *(const f4*)&wr_s[k * HID + tx * 8]; \
        f4 wr1 = *(const f4*)&wr_s[k * HID + tx * 8 + 4]; \
        accA[0] += av0.x * wl0 + hv0.x * wr0;  accB[0] += av0.x * wl1 + hv0.x * wr1; \
        accA[1] += av0.y * wl0 + hv0.y * wr0;  accB[1] += av0.y * wl1 + hv0.y * wr1; \
        accA[2] += av0.z * wl0 + hv0.z * wr0;  accB[2] += av0.z * wl1 + hv0.z * wr1; \
        accA[3] += av0.w * wl0 + hv0.w * wr0;  accB[3] += av0.w * wl1 + hv0.w * wr1; \
        accA[4] += av1.x * wl0 + hv1.x * wr0;  accB[4] += av1.x * wl1 + hv1.x * wr1; \
        accA[5] += av1.y * wl0 + hv1.y * wr0;  accB[5] += av1.y * wl1 + hv1.y * wr1; \
        accA[6] += av1.z * wl0 + hv1.z * wr0;  accB[6] += av1.z * wl1 + hv1.z * wr1; \
        accA[7] += av1.w * wl0 + hv1.w * wr0;  accB[7] += av1.w * wl1 + hv1.w * wr1; \
      } \
    } \
  }

__global__ __launch_bounds__(256, 3)
void gemm_kernel(const float* __restrict__ aggr,
                 const float* hin,
                 const float* __restrict__ Wl, const float* __restrict__ bl,
                 const float* __restrict__ Wr,
                 float* hout, int n) {
  __shared__ float a_s[BKG * XT_STRIDE];
  __shared__ float h_s[BKG * XT_STRIDE];
  __shared__ float wl_s[BKG * HID];
  __shared__ float wr_s[BKG * HID];
  int t = threadIdx.x;
  int tx = t & 7;
  int ng = t >> 3;
  int n0 = blockIdx.x * 256;

  f4 b0 = ((const f4*)bl)[tx * 2];
  f4 b1 = ((const f4*)bl)[tx * 2 + 1];
  f4 accA[8], accB[8];
  #pragma unroll
  for (int i = 0; i < 8; ++i) { accA[i] = b0; accB[i] = b1; }

  GEMM_BODY(aggr, hin)

  #pragma unroll
  for (int i = 0; i < 8; ++i) {
    int node = n0 + ng * 8 + i;
    if (node < n) {
      f4 a = accA[i], b = accB[i];
      RELU4(a) RELU4(b)
      *(f4*)&hout[(size_t)node * HID + tx * 8] = a;
      *(f4*)&hout[(size_t)node * HID + tx * 8 + 4] = b;
    }
  }
}

// ---------------- gemm2 + cls fused ---------------------------------------
__global__ __launch_bounds__(256, 3)
void gemm_cls_kernel(const float* __restrict__ aggr,
                     const float* __restrict__ hin,
                     const float* __restrict__ Wl, const float* __restrict__ bl,
                     const float* __restrict__ Wr,
                     const float* __restrict__ Wc, const float* __restrict__ bc,
                     float* __restrict__ out, int n) {
  __shared__ float a_s[BKG * XT_STRIDE];
  __shared__ float h_s[BKG * XT_STRIDE];
  __shared__ float wl_s[BKG * HID];
  __shared__ float wr_s[BKG * HID];
  int t = threadIdx.x;
  int tx = t & 7;
  int ng = t >> 3;
  int n0 = blockIdx.x * 256;

  f4 b0 = ((const f4*)bl)[tx * 2];
  f4 b1 = ((const f4*)bl)[tx * 2 + 1];
  f4 accA[8], accB[8];
  #pragma unroll
  for (int i = 0; i < 8; ++i) { accA[i] = b0; accB[i] = b1; }

  GEMM_BODY(aggr, hin)

  f4 wc0 = ((const f4*)Wc)[tx * 2];
  f4 wc1 = ((const f4*)Wc)[tx * 2 + 1];
  float bcv = bc[0];
  #pragma unroll
  for (int i = 0; i < 8; ++i) {
    f4 a = accA[i], b = accB[i];
    RELU4(a) RELU4(b)
    float s = a.x * wc0.x + a.y * wc0.y + a.z * wc0.z + a.w * wc0.w
            + b.x * wc1.x + b.y * wc1.y + b.z * wc1.z + b.w * wc1.w;
    s += __shfl_xor(s, 1, 64);
    s += __shfl_xor(s, 2, 64);
    s += __shfl_xor(s, 4, 64);
    int node = n0 + ng * 8 + i;
    if (tx == 0 && node < n) out[node] = s + bcv;
  }
}

extern "C" void kernel_launch(void* const* d_in, const int* in_sizes, int n_in,
                              void* d_out, int out_size, void* d_ws, size_t ws_size,
                              hipStream_t stream) {
  const float* x   = (const float*)d_in[0];
  const int*   ei  = (const int*)d_in[1];
  const float* Wp  = (const float*)d_in[2];
  const float* bp  = (const float*)d_in[3];
  const float* W1l = (const float*)d_in[4];
  const float* b1l = (const float*)d_in[5];
  const float* W1r = (const float*)d_in[6];
  const float* W2l = (const float*)d_in[7];
  const float* b2l = (const float*)d_in[8];
  const float* W2r = (const float*)d_in[9];
  const float* Wc  = (const float*)d_in[10];
  const float* bc  = (const float*)d_in[11];
  float* out = (float*)d_out;

  const int N = NNODES, E = NEDGES;
  const int* src = ei;
  const int* dst = ei + E;

  char* ws = (char*)d_ws;
  float* h       = (float*)(ws + 0);          // 51,200,000 B
  float* aggr    = (float*)(ws + 51200000);   // 51,200,000 B
  int*   p_src   = (int*)  (ws + 51200000);   // alias aggr: 8*416000*4 = 13,312,000 B
  int*   p_dst   = p_src + (size_t)NR * CAP;  //            +13,312,000 B (< 51.2MB)
  int*   counts  = (int*)  (ws + 102400000);  // 800,000 B
  int*   gbase   = (int*)  (ws + 103200000);  // 32 B (contiguous with counts)
  int*   row_ptr = (int*)  (ws + 103200032);  // 800,004 B
  int*   cursor  = (int*)  (ws + 104000064);  // 800,000 B
  int*   csr_src = (int*)  (ws + 104800064);  // 12,800,000 B
  int*   bsums   = (int*)  (ws + 117600064);  // ~400 B

  // zero counts + gbase in one memset (contiguous)
  hipMemsetAsync(counts, 0, (size_t)N * 4 + NR * 4, stream);

  proj_kernel<<<782, 256, 0, stream>>>(x, Wp, bp, h, N);

  int nchunksA = (E + ACHUNK - 1) / ACHUNK;            // 782
  bucket_kernel<<<nchunksA, 256, 0, stream>>>(src, dst, gbase, p_src, p_dst, E);

  int nchunksB = (CAP + ACHUNK - 1) / ACHUNK;          // 102
  bdeg_kernel<<<nchunksB * NR, 256, 0, stream>>>(gbase, p_dst, counts);

  int nb = (N + SCAN_CHUNK - 1) / SCAN_CHUNK;
  scan1_kernel<<<nb, SCAN_T, 0, stream>>>(counts, row_ptr, bsums, N);
  scan2_kernel<<<1, SCAN_T, 0, stream>>>(bsums, nb);
  scan3_kernel<<<(N + 256) / 256, 256, 0, stream>>>(row_ptr, bsums, cursor, N, E);

  bscatter_kernel<<<nchunksB * NR, 256, 0, stream>>>(gbase, p_src, p_dst, cursor, csr_src);

  aggr_kernel<<<(N + 3) / 4, 256, 0, stream>>>(h, row_ptr, csr_src, aggr, N);
  gemm_kernel<<<782, 256, 0, stream>>>(aggr, h, W1l, b1l, W1r, h, N);

  aggr_kernel<<<(N + 3) / 4, 256, 0, stream>>>(h, row_ptr, csr_src, aggr, N);
  gemm_cls_kernel<<<782, 256, 0, stream>>>(aggr, h, W2l, b2l, W2r, Wc, bc, out, N);
}

// Round 2
// 1004.619 us; speedup vs baseline: 1.2189x; 1.2189x over previous
//
#include <hip/hip_runtime.h>
#include <hip/hip_bf16.h>

// GraphSAGE forward: proj -> [aggr -> gemm] x2 (+cls fused into gemm2)
// N=200000, E=3200000, IN_DIM=165, HID=64. All fp32.
//
// R10 design notes:
//  - post-mortem R9: register double-buffered staging SPILLED to scratch
//    (gemm VGPR=84 but needs ~140 live; WRITE_SIZE 184MB for a 51MB output,
//    FETCH +115MB -- symmetric scratch traffic). Reverted.
//  - real occupancy limit was the GRID: 782 blocks = 3.05/CU. R10 matmuls
//    use 128-node blocks (4x8 micro-tile, acc=32 VGPR, gemm LDS 25KB ->
//    6 blocks/CU, grid 1563). Staging latency hidden by TLP, not prefetch.
//  - CSR build kept from R9: bucket (1 pass, in-block scans, dense bucket
//    windows) -> per-bucket XCD-local degree + scatter.
//  - cls fused into gemm2.

#define NNODES 200000
#define NEDGES 3200000
#define INDIM 165
#define HID 64

#define NR 8
#define RSIZE (NNODES / NR)   // 25000
#define CAP 416000            // per-bucket capacity
#define ACHUNK 4096

#define SCAN_T 256
#define SCAN_I 8
#define SCAN_CHUNK (SCAN_T * SCAN_I)

#define BKP 15            // proj K chunk: 165 = 11*15
#define BKG 16            // gemm K chunk: 64 = 4*16
#define NPB 128           // nodes per matmul block
#define XSTR 132          // 128 + 4 pad, %4==0 (f4 aligned)

typedef float f4 __attribute__((ext_vector_type(4)));

#define RELU4(v) { v.x=fmaxf(v.x,0.f); v.y=fmaxf(v.y,0.f); v.z=fmaxf(v.z,0.f); v.w=fmaxf(v.w,0.f); }

// 4-node x 8-out micro-tile FMA (single input matrix)
#define MT_FMA1(xv, wv0, wv1) \
  accA[0] += xv.x * wv0; accB[0] += xv.x * wv1; \
  accA[1] += xv.y * wv0; accB[1] += xv.y * wv1; \
  accA[2] += xv.z * wv0; accB[2] += xv.z * wv1; \
  accA[3] += xv.w * wv0; accB[3] += xv.w * wv1;

// ---------------- proj: h = relu(x @ Wp + bp) -----------------------------
__global__ __launch_bounds__(256, 4)
void proj_kernel(const float* __restrict__ x,
                 const float* __restrict__ Wp,
                 const float* __restrict__ bp,
                 float* __restrict__ h, int n) {
  __shared__ float x_s[BKP * XSTR];
  __shared__ float w_s[BKP * HID];
  int t = threadIdx.x;
  int tx = t & 7;       // out group: cols tx*8..tx*8+7
  int ng = t >> 3;      // node group: nodes ng*4..ng*4+3
  int n0 = blockIdx.x * NPB;

  f4 b0 = ((const f4*)bp)[tx * 2];
  f4 b1 = ((const f4*)bp)[tx * 2 + 1];
  f4 accA[4], accB[4];
  #pragma unroll
  for (int i = 0; i < 4; ++i) { accA[i] = b0; accB[i] = b1; }

  for (int kc = 0; kc < INDIM / BKP; ++kc) {
    for (int i = t; i < NPB * BKP; i += 256) {
      int node = i / BKP, col = i - node * BKP;
      int gi = n0 + node; if (gi >= n) gi = n - 1;
      x_s[col * XSTR + node] = x[(size_t)gi * INDIM + kc * BKP + col];
    }
    if (t < BKP * HID / 4)
      ((f4*)w_s)[t] = ((const f4*)(Wp + kc * BKP * HID))[t];
    __syncthreads();
    #pragma unroll
    for (int k = 0; k < BKP; ++k) {
      f4 xv = *(const f4*)&x_s[k * XSTR + ng * 4];
      f4 wv0 = *(const f4*)&w_s[k * HID + tx * 8];
      f4 wv1 = *(const f4*)&w_s[k * HID + tx * 8 + 4];
      MT_FMA1(xv, wv0, wv1)
    }
    __syncthreads();
  }
  #pragma unroll
  for (int i = 0; i < 4; ++i) {
    int node = n0 + ng * 4 + i;
    if (node < n) {
      f4 a = accA[i], b = accB[i];
      RELU4(a) RELU4(b)
      *(f4*)&h[(size_t)node * HID + tx * 8] = a;
      *(f4*)&h[(size_t)node * HID + tx * 8 + 4] = b;
    }
  }
}

// ---------------- phase A: bucket edges by dst range ----------------------
__global__ __launch_bounds__(256)
void bucket_kernel(const int* __restrict__ src, const int* __restrict__ dst,
                   int* __restrict__ gbase,
                   int* __restrict__ p_src, int* __restrict__ p_dst, int e) {
  __shared__ int wpart[4][NR];
  __shared__ int wbase[4][NR];
  __shared__ int bbase[NR];
  __shared__ int posm[NR][256];
  int t = threadIdx.x;
  int lane = t & 63, wid = t >> 6;
  int base = blockIdx.x * ACHUNK;

  int dreg[16];
  int c[NR];
  #pragma unroll
  for (int r = 0; r < NR; ++r) c[r] = 0;
  #pragma unroll
  for (int j = 0; j < 16; ++j) {
    int i = base + t + j * 256;
    int d = (i < e) ? __builtin_nontemporal_load(&dst[i]) : -1;
    dreg[j] = d;
    if (d >= 0) c[d / RSIZE]++;
  }
  int excl[NR];
  #pragma unroll
  for (int r = 0; r < NR; ++r) {
    int v = c[r];
    int incl = v;
    #pragma unroll
    for (int off = 1; off < 64; off <<= 1) {
      int y = __shfl_up(incl, off, 64);
      if (lane >= off) incl += y;
    }
    excl[r] = incl - v;
    if (lane == 63) wpart[wid][r] = incl;
  }
  __syncthreads();
  if (t < NR) {
    int s0 = wpart[0][t], s1 = wpart[1][t], s2 = wpart[2][t], s3 = wpart[3][t];
    int tot = s0 + s1 + s2 + s3;
    bbase[t] = atomicAdd(&gbase[t], tot);
    wbase[0][t] = 0; wbase[1][t] = s0; wbase[2][t] = s0 + s1; wbase[3][t] = s0 + s1 + s2;
  }
  __syncthreads();
  #pragma unroll
  for (int r = 0; r < NR; ++r)
    posm[r][t] = r * CAP + bbase[r] + wbase[wid][r] + excl[r];
  #pragma unroll
  for (int j = 0; j < 16; ++j) {
    int d = dreg[j];
    if (d >= 0) {
      int s = __builtin_nontemporal_load(&src[base + t + j * 256]);
      int r = d / RSIZE;
      int p = posm[r][t]++;
      p_dst[p] = d;
      p_src[p] = s;
    }
  }
}

// ---------------- phase B1: per-bucket degree histogram -------------------
__global__ void bdeg_kernel(const int* __restrict__ gbase,
                            const int* __restrict__ p_dst,
                            int* __restrict__ counts) {
  int r = blockIdx.x & (NR - 1);
  int chunk = blockIdx.x >> 3;
  int n_r = gbase[r];
  int base = chunk * ACHUNK;
  if (base >= n_r) return;
  int end = min(base + ACHUNK, n_r);
  const int* pd = p_dst + (size_t)r * CAP;
  for (int i = base + (int)threadIdx.x; i < end; i += 256) {
    int d = __builtin_nontemporal_load(&pd[i]);
    atomicAdd(&counts[d], 1);
  }
}

// ---------------- scan ----------------------------------------------------
__global__ void scan1_kernel(const int* __restrict__ counts, int* __restrict__ row_ptr,
                             int* __restrict__ bsums, int n) {
  __shared__ int lds[SCAN_T];
  int b = blockIdx.x, t = threadIdx.x;
  int base = b * SCAN_CHUNK + t * SCAN_I;
  int v[SCAN_I];
  int s = 0;
  #pragma unroll
  for (int i = 0; i < SCAN_I; ++i) {
    int idx = base + i;
    v[i] = (idx < n) ? counts[idx] : 0;
    s += v[i];
  }
  lds[t] = s;
  __syncthreads();
  for (int off = 1; off < SCAN_T; off <<= 1) {
    int y = (t >= off) ? lds[t - off] : 0;
    __syncthreads();
    lds[t] += y;
    __syncthreads();
  }
  int incl = lds[t];
  int run = incl - s;
  #pragma unroll
  for (int i = 0; i < SCAN_I; ++i) {
    int idx = base + i;
    if (idx < n) row_ptr[idx] = run;
    run += v[i];
  }
  if (t == SCAN_T - 1) bsums[b] = incl;
}

__global__ void scan2_kernel(int* __restrict__ bsums, int nb) {
  __shared__ int lds[SCAN_T];
  int t = threadIdx.x;
  int v = (t < nb) ? bsums[t] : 0;
  lds[t] = v;
  __syncthreads();
  for (int off = 1; off < SCAN_T; off <<= 1) {
    int y = (t >= off) ? lds[t - off] : 0;
    __syncthreads();
    lds[t] += y;
    __syncthreads();
  }
  if (t < nb) bsums[t] = lds[t] - v;
}

__global__ void scan3_kernel(int* __restrict__ row_ptr, const int* __restrict__ bsums,
                             int* __restrict__ cursor, int n, int e) {
  int i = blockIdx.x * blockDim.x + threadIdx.x;
  if (i < n) {
    int v = row_ptr[i] + bsums[i / SCAN_CHUNK];
    row_ptr[i] = v;
    cursor[i] = v;
  }
  if (i == n) row_ptr[n] = e;
}

// ---------------- phase B2: per-bucket scatter into CSR -------------------
__global__ void bscatter_kernel(const int* __restrict__ gbase,
                                const int* __restrict__ p_src,
                                const int* __restrict__ p_dst,
                                int* __restrict__ cursor, int* __restrict__ csr_src) {
  int r = blockIdx.x & (NR - 1);
  int chunk = blockIdx.x >> 3;
  int n_r = gbase[r];
  int base = chunk * ACHUNK;
  if (base >= n_r) return;
  int end = min(base + ACHUNK, n_r);
  const int* pd = p_dst + (size_t)r * CAP;
  const int* ps = p_src + (size_t)r * CAP;
  for (int i = base + (int)threadIdx.x; i < end; i += 256) {
    int d = __builtin_nontemporal_load(&pd[i]);
    int s = __builtin_nontemporal_load(&ps[i]);
    int pos = atomicAdd(&cursor[d], 1);
    csr_src[pos] = s;
  }
}

// ---------------- mean aggregation (pull, CSR) ----------------------------
__global__ void aggr_kernel(const float* __restrict__ hin,
                            const int* __restrict__ row_ptr,
                            const int* __restrict__ csr_src,
                            float* __restrict__ aggr, int n) {
  int lane = threadIdx.x & 63;
  int grp = lane >> 4, sub = lane & 15;
  int node = (blockIdx.x * blockDim.x + threadIdx.x) >> 6;
  if (node >= n) return;
  int r0 = row_ptr[node], r1 = row_ptr[node + 1];
  f4 acc0 = {0.f, 0.f, 0.f, 0.f}, acc1 = {0.f, 0.f, 0.f, 0.f};
  int p = r0;
  for (; p + 8 <= r1; p += 8) {
    int i0 = csr_src[p + grp];
    int i1 = csr_src[p + 4 + grp];
    f4 v0 = *((const f4*)(hin + (size_t)i0 * HID) + sub);
    f4 v1 = *((const f4*)(hin + (size_t)i1 * HID) + sub);
    acc0 += v0;
    acc1 += v1;
  }
  if (p + 4 <= r1) {
    int i0 = csr_src[p + grp];
    acc0 += *((const f4*)(hin + (size_t)i0 * HID) + sub);
    p += 4;
  }
  int rem = r1 - p;
  if (grp < rem) {
    int i0 = csr_src[p + grp];
    acc1 += *((const f4*)(hin + (size_t)i0 * HID) + sub);
  }
  acc0 += acc1;
  #pragma unroll
  for (int c = 0; c < 4; ++c) {
    float v = acc0[c];
    v += __shfl_xor(v, 16, 64);
    v += __shfl_xor(v, 32, 64);
    acc0[c] = v;
  }
  int deg = r1 - r0;
  float rdeg = 1.f / (float)(deg > 1 ? deg : 1);
  if (grp == 0) {
    f4 o = acc0 * rdeg;
    *((f4*)(aggr + (size_t)node * HID) + sub) = o;
  }
}

// ---------------- gemm: hout = relu(aggr@Wl + bl + hin@Wr) ---------------
// single-buffered staging, 128-node block, 4x8 micro-tile
#define GEMM_BODY(aggrp, hinp) \
  for (int kc = 0; kc < HID / BKG; ++kc) { \
    for (int i = t; i < NPB * BKG; i += 256) { \
      int node = i >> 4, k = i & 15; \
      int gi = n0 + node; if (gi >= n) gi = n - 1; \
      a_s[k * XSTR + node] = aggrp[(size_t)gi * HID + kc * BKG + k]; \
      h_s[k * XSTR + node] = hinp[(size_t)gi * HID + kc * BKG + k]; \
    } \
    ((f4*)wl_s)[t] = ((const f4*)(Wl + kc * BKG * HID))[t]; \
    ((f4*)wr_s)[t] = ((const f4*)(Wr + kc * BKG * HID))[t]; \
    __syncthreads(); \
    _Pragma("unroll") \
    for (int k = 0; k < BKG; ++k) { \
      f4 av = *(const f4*)&a_s[k * XSTR + ng * 4]; \
      f4 hv = *(const f4*)&h_s[k * XSTR + ng * 4]; \
      f4 wl0 = *(const f4*)&wl_s[k * HID + tx * 8]; \
      f4 wl1 = *(const f4*)&wl_s[k * HID + tx * 8 + 4]; \
      f4 wr0 = *(const f4*)&wr_s[k * HID + tx * 8]; \
      f4 wr1 = *(const f4*)&wr_s[k * HID + tx * 8 + 4]; \
      accA[0] += av.x * wl0 + hv.x * wr0;  accB[0] += av.x * wl1 + hv.x * wr1; \
      accA[1] += av.y * wl0 + hv.y * wr0;  accB[1] += av.y * wl1 + hv.y * wr1; \
      accA[2] += av.z * wl0 + hv.z * wr0;  accB[2] += av.z * wl1 + hv.z * wr1; \
      accA[3] += av.w * wl0 + hv.w * wr0;  accB[3] += av.w * wl1 + hv.w * wr1; \
    } \
    __syncthreads(); \
  }

__global__ __launch_bounds__(256, 4)
void gemm_kernel(const float* __restrict__ aggr,
                 const float* hin,
                 const float* __restrict__ Wl, const float* __restrict__ bl,
                 const float* __restrict__ Wr,
                 float* hout, int n) {
  __shared__ float a_s[BKG * XSTR];
  __shared__ float h_s[BKG * XSTR];
  __shared__ float wl_s[BKG * HID];
  __shared__ float wr_s[BKG * HID];
  int t = threadIdx.x;
  int tx = t & 7;
  int ng = t >> 3;
  int n0 = blockIdx.x * NPB;

  f4 b0 = ((const f4*)bl)[tx * 2];
  f4 b1 = ((const f4*)bl)[tx * 2 + 1];
  f4 accA[4], accB[4];
  #pragma unroll
  for (int i = 0; i < 4; ++i) { accA[i] = b0; accB[i] = b1; }

  GEMM_BODY(aggr, hin)

  #pragma unroll
  for (int i = 0; i < 4; ++i) {
    int node = n0 + ng * 4 + i;
    if (node < n) {
      f4 a = accA[i], b = accB[i];
      RELU4(a) RELU4(b)
      *(f4*)&hout[(size_t)node * HID + tx * 8] = a;
      *(f4*)&hout[(size_t)node * HID + tx * 8 + 4] = b;
    }
  }
}

// ---------------- gemm2 + cls fused ---------------------------------------
__global__ __launch_bounds__(256, 4)
void gemm_cls_kernel(const float* __restrict__ aggr,
                     const float* __restrict__ hin,
                     const float* __restrict__ Wl, const float* __restrict__ bl,
                     const float* __restrict__ Wr,
                     const float* __restrict__ Wc, const float* __restrict__ bc,
                     float* __restrict__ out, int n) {
  __shared__ float a_s[BKG * XSTR];
  __shared__ float h_s[BKG * XSTR];
  __shared__ float wl_s[BKG * HID];
  __shared__ float wr_s[BKG * HID];
  int t = threadIdx.x;
  int tx = t & 7;
  int ng = t >> 3;
  int n0 = blockIdx.x * NPB;

  f4 b0 = ((const f4*)bl)[tx * 2];
  f4 b1 = ((const f4*)bl)[tx * 2 + 1];
  f4 accA[4], accB[4];
  #pragma unroll
  for (int i = 0; i < 4; ++i) { accA[i] = b0; accB[i] = b1; }

  GEMM_BODY(aggr, hin)

  f4 wc0 = ((const f4*)Wc)[tx * 2];
  f4 wc1 = ((const f4*)Wc)[tx * 2 + 1];
  float bcv = bc[0];
  #pragma unroll
  for (int i = 0; i < 4; ++i) {
    f4 a = accA[i], b = accB[i];
    RELU4(a) RELU4(b)
    float s = a.x * wc0.x + a.y * wc0.y + a.z * wc0.z + a.w * wc0.w
            + b.x * wc1.x + b.y * wc1.y + b.z * wc1.z + b.w * wc1.w;
    s += __shfl_xor(s, 1, 64);
    s += __shfl_xor(s, 2, 64);
    s += __shfl_xor(s, 4, 64);
    int node = n0 + ng * 4 + i;
    if (tx == 0 && node < n) out[node] = s + bcv;
  }
}

extern "C" void kernel_launch(void* const* d_in, const int* in_sizes, int n_in,
                              void* d_out, int out_size, void* d_ws, size_t ws_size,
                              hipStream_t stream) {
  const float* x   = (const float*)d_in[0];
  const int*   ei  = (const int*)d_in[1];
  const float* Wp  = (const float*)d_in[2];
  const float* bp  = (const float*)d_in[3];
  const float* W1l = (const float*)d_in[4];
  const float* b1l = (const float*)d_in[5];
  const float* W1r = (const float*)d_in[6];
  const float* W2l = (const float*)d_in[7];
  const float* b2l = (const float*)d_in[8];
  const float* W2r = (const float*)d_in[9];
  const float* Wc  = (const float*)d_in[10];
  const float* bc  = (const float*)d_in[11];
  float* out = (float*)d_out;

  const int N = NNODES, E = NEDGES;
  const int* src = ei;
  const int* dst = ei + E;

  char* ws = (char*)d_ws;
  float* h       = (float*)(ws + 0);          // 51,200,000 B
  float* aggr    = (float*)(ws + 51200000);   // 51,200,000 B
  int*   p_src   = (int*)  (ws + 51200000);   // alias aggr (dead until after scatter)
  int*   p_dst   = p_src + (size_t)NR * CAP;
  int*   counts  = (int*)  (ws + 102400000);  // 800,000 B
  int*   gbase   = (int*)  (ws + 103200000);  // 32 B (contiguous with counts)
  int*   row_ptr = (int*)  (ws + 103200032);  // 800,004 B
  int*   cursor  = (int*)  (ws + 104000064);  // 800,000 B
  int*   csr_src = (int*)  (ws + 104800064);  // 12,800,000 B
  int*   bsums   = (int*)  (ws + 117600064);  // ~400 B

  hipMemsetAsync(counts, 0, (size_t)N * 4 + NR * 4, stream);

  int mgrid = (N + NPB - 1) / NPB;                     // 1563
  proj_kernel<<<mgrid, 256, 0, stream>>>(x, Wp, bp, h, N);

  int nchunksA = (E + ACHUNK - 1) / ACHUNK;            // 782
  bucket_kernel<<<nchunksA, 256, 0, stream>>>(src, dst, gbase, p_src, p_dst, E);

  int nchunksB = (CAP + ACHUNK - 1) / ACHUNK;          // 102
  bdeg_kernel<<<nchunksB * NR, 256, 0, stream>>>(gbase, p_dst, counts);

  int nb = (N + SCAN_CHUNK - 1) / SCAN_CHUNK;
  scan1_kernel<<<nb, SCAN_T, 0, stream>>>(counts, row_ptr, bsums, N);
  scan2_kernel<<<1, SCAN_T, 0, stream>>>(bsums, nb);
  scan3_kernel<<<(N + 256) / 256, 256, 0, stream>>>(row_ptr, bsums, cursor, N, E);

  bscatter_kernel<<<nchunksB * NR, 256, 0, stream>>>(gbase, p_src, p_dst, cursor, csr_src);

  aggr_kernel<<<(N + 3) / 4, 256, 0, stream>>>(h, row_ptr, csr_src, aggr, N);
  gemm_kernel<<<mgrid, 256, 0, stream>>>(aggr, h, W1l, b1l, W1r, h, N);

  aggr_kernel<<<(N + 3) / 4, 256, 0, stream>>>(h, row_ptr, csr_src, aggr, N);
  gemm_cls_kernel<<<mgrid, 256, 0, stream>>>(aggr, h, W2l, b2l, W2r, Wc, bc, out, N);
}

// Round 3
// 969.715 us; speedup vs baseline: 1.2628x; 1.0360x over previous
//
#include <hip/hip_runtime.h>
#include <hip/hip_bf16.h>

// GraphSAGE forward: proj -> [aggr -> gemm] x2 (+cls fused into gemm2)
// N=200000, E=3200000, IN_DIM=165, HID=64. All fp32.
//
// R11 design notes:
//  - post-mortem R10: bscatter WRITE=155MB for 12.8MB payload. Cause: the
//    blockIdx&7 -> XCD assumption is invalid (dispatch undefined), so each
//    csr slice was dirty in MULTIPLE XCD L2s -> every partial 64B line
//    written back per-XCD (byte-masked, correct but 12x WRITE amp).
//  - fix: bscatter blocks read their REAL XCD via s_getreg(HW_REG_XCC_ID)
//    and work-steal chunks of bucket r == XCC_ID only (per-bucket atomic
//    chunk counter). csr slice r is then dirty in exactly one L2.
//  - degree histogram fused into bucket_kernel (d already in regs);
//    bdeg_kernel deleted (-13MB re-read, -1 launch).
//  - matmuls: 128-node blocks, 4x8 micro-tile (R10, no scratch spill).
//  - cls fused into gemm2.

#define NNODES 200000
#define NEDGES 3200000
#define INDIM 165
#define HID 64

#define NR 8
#define RSIZE (NNODES / NR)   // 25000
#define CAP 416000            // per-bucket capacity
#define ACHUNK 4096

#define SCAN_T 256
#define SCAN_I 8
#define SCAN_CHUNK (SCAN_T * SCAN_I)

#define BKP 15            // proj K chunk: 165 = 11*15
#define BKG 16            // gemm K chunk: 64 = 4*16
#define NPB 128           // nodes per matmul block
#define XSTR 132          // 128 + 4 pad, %4==0 (f4 aligned)

typedef float f4 __attribute__((ext_vector_type(4)));

#define RELU4(v) { v.x=fmaxf(v.x,0.f); v.y=fmaxf(v.y,0.f); v.z=fmaxf(v.z,0.f); v.w=fmaxf(v.w,0.f); }

#define MT_FMA1(xv, wv0, wv1) \
  accA[0] += xv.x * wv0; accB[0] += xv.x * wv1; \
  accA[1] += xv.y * wv0; accB[1] += xv.y * wv1; \
  accA[2] += xv.z * wv0; accB[2] += xv.z * wv1; \
  accA[3] += xv.w * wv0; accB[3] += xv.w * wv1;

// ---------------- proj: h = relu(x @ Wp + bp) -----------------------------
__global__ __launch_bounds__(256, 4)
void proj_kernel(const float* __restrict__ x,
                 const float* __restrict__ Wp,
                 const float* __restrict__ bp,
                 float* __restrict__ h, int n) {
  __shared__ float x_s[BKP * XSTR];
  __shared__ float w_s[BKP * HID];
  int t = threadIdx.x;
  int tx = t & 7;
  int ng = t >> 3;
  int n0 = blockIdx.x * NPB;

  f4 b0 = ((const f4*)bp)[tx * 2];
  f4 b1 = ((const f4*)bp)[tx * 2 + 1];
  f4 accA[4], accB[4];
  #pragma unroll
  for (int i = 0; i < 4; ++i) { accA[i] = b0; accB[i] = b1; }

  for (int kc = 0; kc < INDIM / BKP; ++kc) {
    for (int i = t; i < NPB * BKP; i += 256) {
      int node = i / BKP, col = i - node * BKP;
      int gi = n0 + node; if (gi >= n) gi = n - 1;
      x_s[col * XSTR + node] = x[(size_t)gi * INDIM + kc * BKP + col];
    }
    if (t < BKP * HID / 4)
      ((f4*)w_s)[t] = ((const f4*)(Wp + kc * BKP * HID))[t];
    __syncthreads();
    #pragma unroll
    for (int k = 0; k < BKP; ++k) {
      f4 xv = *(const f4*)&x_s[k * XSTR + ng * 4];
      f4 wv0 = *(const f4*)&w_s[k * HID + tx * 8];
      f4 wv1 = *(const f4*)&w_s[k * HID + tx * 8 + 4];
      MT_FMA1(xv, wv0, wv1)
    }
    __syncthreads();
  }
  #pragma unroll
  for (int i = 0; i < 4; ++i) {
    int node = n0 + ng * 4 + i;
    if (node < n) {
      f4 a = accA[i], b = accB[i];
      RELU4(a) RELU4(b)
      *(f4*)&h[(size_t)node * HID + tx * 8] = a;
      *(f4*)&h[(size_t)node * HID + tx * 8 + 4] = b;
    }
  }
}

// ---------------- phase A: bucket edges by dst range + degree -------------
__global__ __launch_bounds__(256)
void bucket_kernel(const int* __restrict__ src, const int* __restrict__ dst,
                   int* __restrict__ gbase,
                   int* __restrict__ p_src, int* __restrict__ p_dst,
                   int* __restrict__ counts, int e) {
  __shared__ int wpart[4][NR];
  __shared__ int wbase[4][NR];
  __shared__ int bbase[NR];
  __shared__ int posm[NR][256];
  int t = threadIdx.x;
  int lane = t & 63, wid = t >> 6;
  int base = blockIdx.x * ACHUNK;

  int dreg[16];
  int c[NR];
  #pragma unroll
  for (int r = 0; r < NR; ++r) c[r] = 0;
  #pragma unroll
  for (int j = 0; j < 16; ++j) {
    int i = base + t + j * 256;
    int d = (i < e) ? __builtin_nontemporal_load(&dst[i]) : -1;
    dreg[j] = d;
    if (d >= 0) c[d / RSIZE]++;
  }
  int excl[NR];
  #pragma unroll
  for (int r = 0; r < NR; ++r) {
    int v = c[r];
    int incl = v;
    #pragma unroll
    for (int off = 1; off < 64; off <<= 1) {
      int y = __shfl_up(incl, off, 64);
      if (lane >= off) incl += y;
    }
    excl[r] = incl - v;
    if (lane == 63) wpart[wid][r] = incl;
  }
  __syncthreads();
  if (t < NR) {
    int s0 = wpart[0][t], s1 = wpart[1][t], s2 = wpart[2][t], s3 = wpart[3][t];
    int tot = s0 + s1 + s2 + s3;
    bbase[t] = atomicAdd(&gbase[t], tot);
    wbase[0][t] = 0; wbase[1][t] = s0; wbase[2][t] = s0 + s1; wbase[3][t] = s0 + s1 + s2;
  }
  __syncthreads();
  #pragma unroll
  for (int r = 0; r < NR; ++r)
    posm[r][t] = r * CAP + bbase[r] + wbase[wid][r] + excl[r];
  #pragma unroll
  for (int j = 0; j < 16; ++j) {
    int d = dreg[j];
    if (d >= 0) {
      int s = __builtin_nontemporal_load(&src[base + t + j * 256]);
      int r = d / RSIZE;
      int p = posm[r][t]++;
      p_dst[p] = d;
      p_src[p] = s;
      atomicAdd(&counts[d], 1);   // fused degree histogram (fire-and-forget)
    }
  }
}

// ---------------- scan ----------------------------------------------------
__global__ void scan1_kernel(const int* __restrict__ counts, int* __restrict__ row_ptr,
                             int* __restrict__ bsums, int n) {
  __shared__ int lds[SCAN_T];
  int b = blockIdx.x, t = threadIdx.x;
  int base = b * SCAN_CHUNK + t * SCAN_I;
  int v[SCAN_I];
  int s = 0;
  #pragma unroll
  for (int i = 0; i < SCAN_I; ++i) {
    int idx = base + i;
    v[i] = (idx < n) ? counts[idx] : 0;
    s += v[i];
  }
  lds[t] = s;
  __syncthreads();
  for (int off = 1; off < SCAN_T; off <<= 1) {
    int y = (t >= off) ? lds[t - off] : 0;
    __syncthreads();
    lds[t] += y;
    __syncthreads();
  }
  int incl = lds[t];
  int run = incl - s;
  #pragma unroll
  for (int i = 0; i < SCAN_I; ++i) {
    int idx = base + i;
    if (idx < n) row_ptr[idx] = run;
    run += v[i];
  }
  if (t == SCAN_T - 1) bsums[b] = incl;
}

__global__ void scan2_kernel(int* __restrict__ bsums, int nb) {
  __shared__ int lds[SCAN_T];
  int t = threadIdx.x;
  int v = (t < nb) ? bsums[t] : 0;
  lds[t] = v;
  __syncthreads();
  for (int off = 1; off < SCAN_T; off <<= 1) {
    int y = (t >= off) ? lds[t - off] : 0;
    __syncthreads();
    lds[t] += y;
    __syncthreads();
  }
  if (t < nb) bsums[t] = lds[t] - v;
}

__global__ void scan3_kernel(int* __restrict__ row_ptr, const int* __restrict__ bsums,
                             int* __restrict__ cursor, int n, int e) {
  int i = blockIdx.x * blockDim.x + threadIdx.x;
  if (i < n) {
    int v = row_ptr[i] + bsums[i / SCAN_CHUNK];
    row_ptr[i] = v;
    cursor[i] = v;
  }
  if (i == n) row_ptr[n] = e;
}

// ---------------- phase B: XCD-pinned scatter into CSR --------------------
// Each block reads its REAL XCD id and only processes bucket r == XCC_ID,
// work-stealing chunks via xctr[r]. csr slice r is dirty in exactly one L2.
__global__ __launch_bounds__(256)
void bscatter_kernel(const int* __restrict__ gbase,
                     const int* __restrict__ p_src,
                     const int* __restrict__ p_dst,
                     int* __restrict__ cursor, int* __restrict__ csr_src,
                     int* __restrict__ xctr) {
  __shared__ int sh_chunk;
  unsigned int xcc;
  asm volatile("s_getreg_b32 %0, hwreg(HW_REG_XCC_ID)" : "=s"(xcc));
  int r = (int)(xcc & (NR - 1));
  int n_r = gbase[r];
  const int* pd = p_dst + (size_t)r * CAP;
  const int* ps = p_src + (size_t)r * CAP;
  for (;;) {
    if (threadIdx.x == 0) sh_chunk = atomicAdd(&xctr[r], 1);
    __syncthreads();
    int base = sh_chunk * ACHUNK;
    __syncthreads();
    if (base >= n_r) return;
    int end = min(base + ACHUNK, n_r);
    for (int i = base + (int)threadIdx.x; i < end; i += 256) {
      int d = __builtin_nontemporal_load(&pd[i]);
      int s = __builtin_nontemporal_load(&ps[i]);
      int pos = atomicAdd(&cursor[d], 1);
      csr_src[pos] = s;
    }
  }
}

// ---------------- mean aggregation (pull, CSR) ----------------------------
__global__ void aggr_kernel(const float* __restrict__ hin,
                            const int* __restrict__ row_ptr,
                            const int* __restrict__ csr_src,
                            float* __restrict__ aggr, int n) {
  int lane = threadIdx.x & 63;
  int grp = lane >> 4, sub = lane & 15;
  int node = (blockIdx.x * blockDim.x + threadIdx.x) >> 6;
  if (node >= n) return;
  int r0 = row_ptr[node], r1 = row_ptr[node + 1];
  f4 acc0 = {0.f, 0.f, 0.f, 0.f}, acc1 = {0.f, 0.f, 0.f, 0.f};
  int p = r0;
  for (; p + 8 <= r1; p += 8) {
    int i0 = csr_src[p + grp];
    int i1 = csr_src[p + 4 + grp];
    f4 v0 = *((const f4*)(hin + (size_t)i0 * HID) + sub);
    f4 v1 = *((const f4*)(hin + (size_t)i1 * HID) + sub);
    acc0 += v0;
    acc1 += v1;
  }
  if (p + 4 <= r1) {
    int i0 = csr_src[p + grp];
    acc0 += *((const f4*)(hin + (size_t)i0 * HID) + sub);
    p += 4;
  }
  int rem = r1 - p;
  if (grp < rem) {
    int i0 = csr_src[p + grp];
    acc1 += *((const f4*)(hin + (size_t)i0 * HID) + sub);
  }
  acc0 += acc1;
  #pragma unroll
  for (int c = 0; c < 4; ++c) {
    float v = acc0[c];
    v += __shfl_xor(v, 16, 64);
    v += __shfl_xor(v, 32, 64);
    acc0[c] = v;
  }
  int deg = r1 - r0;
  float rdeg = 1.f / (float)(deg > 1 ? deg : 1);
  if (grp == 0) {
    f4 o = acc0 * rdeg;
    *((f4*)(aggr + (size_t)node * HID) + sub) = o;
  }
}

// ---------------- gemm: hout = relu(aggr@Wl + bl + hin@Wr) ---------------
#define GEMM_BODY(aggrp, hinp) \
  for (int kc = 0; kc < HID / BKG; ++kc) { \
    for (int i = t; i < NPB * BKG; i += 256) { \
      int node = i >> 4, k = i & 15; \
      int gi = n0 + node; if (gi >= n) gi = n - 1; \
      a_s[k * XSTR + node] = aggrp[(size_t)gi * HID + kc * BKG + k]; \
      h_s[k * XSTR + node] = hinp[(size_t)gi * HID + kc * BKG + k]; \
    } \
    ((f4*)wl_s)[t] = ((const f4*)(Wl + kc * BKG * HID))[t]; \
    ((f4*)wr_s)[t] = ((const f4*)(Wr + kc * BKG * HID))[t]; \
    __syncthreads(); \
    _Pragma("unroll") \
    for (int k = 0; k < BKG; ++k) { \
      f4 av = *(const f4*)&a_s[k * XSTR + ng * 4]; \
      f4 hv = *(const f4*)&h_s[k * XSTR + ng * 4]; \
      f4 wl0 = *(const f4*)&wl_s[k * HID + tx * 8]; \
      f4 wl1 = *(const f4*)&wl_s[k * HID + tx * 8 + 4]; \
      f4 wr0 = *(const f4*)&wr_s[k * HID + tx * 8]; \
      f4 wr1 = *(const f4*)&wr_s[k * HID + tx * 8 + 4]; \
      accA[0] += av.x * wl0 + hv.x * wr0;  accB[0] += av.x * wl1 + hv.x * wr1; \
      accA[1] += av.y * wl0 + hv.y * wr0;  accB[1] += av.y * wl1 + hv.y * wr1; \
      accA[2] += av.z * wl0 + hv.z * wr0;  accB[2] += av.z * wl1 + hv.z * wr1; \
      accA[3] += av.w * wl0 + hv.w * wr0;  accB[3] += av.w * wl1 + hv.w * wr1; \
    } \
    __syncthreads(); \
  }

__global__ __launch_bounds__(256, 4)
void gemm_kernel(const float* __restrict__ aggr,
                 const float* hin,
                 const float* __restrict__ Wl, const float* __restrict__ bl,
                 const float* __restrict__ Wr,
                 float* hout, int n) {
  __shared__ float a_s[BKG * XSTR];
  __shared__ float h_s[BKG * XSTR];
  __shared__ float wl_s[BKG * HID];
  __shared__ float wr_s[BKG * HID];
  int t = threadIdx.x;
  int tx = t & 7;
  int ng = t >> 3;
  int n0 = blockIdx.x * NPB;

  f4 b0 = ((const f4*)bl)[tx * 2];
  f4 b1 = ((const f4*)bl)[tx * 2 + 1];
  f4 accA[4], accB[4];
  #pragma unroll
  for (int i = 0; i < 4; ++i) { accA[i] = b0; accB[i] = b1; }

  GEMM_BODY(aggr, hin)

  #pragma unroll
  for (int i = 0; i < 4; ++i) {
    int node = n0 + ng * 4 + i;
    if (node < n) {
      f4 a = accA[i], b = accB[i];
      RELU4(a) RELU4(b)
      *(f4*)&hout[(size_t)node * HID + tx * 8] = a;
      *(f4*)&hout[(size_t)node * HID + tx * 8 + 4] = b;
    }
  }
}

// ---------------- gemm2 + cls fused ---------------------------------------
__global__ __launch_bounds__(256, 4)
void gemm_cls_kernel(const float* __restrict__ aggr,
                     const float* __restrict__ hin,
                     const float* __restrict__ Wl, const float* __restrict__ bl,
                     const float* __restrict__ Wr,
                     const float* __restrict__ Wc, const float* __restrict__ bc,
                     float* __restrict__ out, int n) {
  __shared__ float a_s[BKG * XSTR];
  __shared__ float h_s[BKG * XSTR];
  __shared__ float wl_s[BKG * HID];
  __shared__ float wr_s[BKG * HID];
  int t = threadIdx.x;
  int tx = t & 7;
  int ng = t >> 3;
  int n0 = blockIdx.x * NPB;

  f4 b0 = ((const f4*)bl)[tx * 2];
  f4 b1 = ((const f4*)bl)[tx * 2 + 1];
  f4 accA[4], accB[4];
  #pragma unroll
  for (int i = 0; i < 4; ++i) { accA[i] = b0; accB[i] = b1; }

  GEMM_BODY(aggr, hin)

  f4 wc0 = ((const f4*)Wc)[tx * 2];
  f4 wc1 = ((const f4*)Wc)[tx * 2 + 1];
  float bcv = bc[0];
  #pragma unroll
  for (int i = 0; i < 4; ++i) {
    f4 a = accA[i], b = accB[i];
    RELU4(a) RELU4(b)
    float s = a.x * wc0.x + a.y * wc0.y + a.z * wc0.z + a.w * wc0.w
            + b.x * wc1.x + b.y * wc1.y + b.z * wc1.z + b.w * wc1.w;
    s += __shfl_xor(s, 1, 64);
    s += __shfl_xor(s, 2, 64);
    s += __shfl_xor(s, 4, 64);
    int node = n0 + ng * 4 + i;
    if (tx == 0 && node < n) out[node] = s + bcv;
  }
}

extern "C" void kernel_launch(void* const* d_in, const int* in_sizes, int n_in,
                              void* d_out, int out_size, void* d_ws, size_t ws_size,
                              hipStream_t stream) {
  const float* x   = (const float*)d_in[0];
  const int*   ei  = (const int*)d_in[1];
  const float* Wp  = (const float*)d_in[2];
  const float* bp  = (const float*)d_in[3];
  const float* W1l = (const float*)d_in[4];
  const float* b1l = (const float*)d_in[5];
  const float* W1r = (const float*)d_in[6];
  const float* W2l = (const float*)d_in[7];
  const float* b2l = (const float*)d_in[8];
  const float* W2r = (const float*)d_in[9];
  const float* Wc  = (const float*)d_in[10];
  const float* bc  = (const float*)d_in[11];
  float* out = (float*)d_out;

  const int N = NNODES, E = NEDGES;
  const int* src = ei;
  const int* dst = ei + E;

  char* ws = (char*)d_ws;
  float* h       = (float*)(ws + 0);          // 51,200,000 B
  float* aggr    = (float*)(ws + 51200000);   // 51,200,000 B
  int*   p_src   = (int*)  (ws + 51200000);   // alias aggr (dead until after scatter)
  int*   p_dst   = p_src + (size_t)NR * CAP;
  int*   counts  = (int*)  (ws + 102400000);  // 800,000 B
  int*   gbase   = (int*)  (ws + 103200000);  // 32 B
  int*   xctr    = (int*)  (ws + 103200032);  // 32 B
  int*   row_ptr = (int*)  (ws + 103200064);  // 800,004 B
  int*   cursor  = (int*)  (ws + 104000096);  // 800,000 B
  int*   csr_src = (int*)  (ws + 104800096);  // 12,800,000 B
  int*   bsums   = (int*)  (ws + 117600096);  // ~400 B

  // zero counts + gbase + xctr in one contiguous memset
  hipMemsetAsync(counts, 0, (size_t)N * 4 + 64, stream);

  int mgrid = (N + NPB - 1) / NPB;                     // 1563
  proj_kernel<<<mgrid, 256, 0, stream>>>(x, Wp, bp, h, N);

  int nchunksA = (E + ACHUNK - 1) / ACHUNK;            // 782
  bucket_kernel<<<nchunksA, 256, 0, stream>>>(src, dst, gbase, p_src, p_dst, counts, E);

  int nb = (N + SCAN_CHUNK - 1) / SCAN_CHUNK;
  scan1_kernel<<<nb, SCAN_T, 0, stream>>>(counts, row_ptr, bsums, N);
  scan2_kernel<<<1, SCAN_T, 0, stream>>>(bsums, nb);
  scan3_kernel<<<(N + 256) / 256, 256, 0, stream>>>(row_ptr, bsums, cursor, N, E);

  bscatter_kernel<<<2048, 256, 0, stream>>>(gbase, p_src, p_dst, cursor, csr_src, xctr);

  aggr_kernel<<<(N + 3) / 4, 256, 0, stream>>>(h, row_ptr, csr_src, aggr, N);
  gemm_kernel<<<mgrid, 256, 0, stream>>>(aggr, h, W1l, b1l, W1r, h, N);

  aggr_kernel<<<(N + 3) / 4, 256, 0, stream>>>(h, row_ptr, csr_src, aggr, N);
  gemm_cls_kernel<<<mgrid, 256, 0, stream>>>(aggr, h, W2l, b2l, W2r, Wc, bc, out, N);
}

// Round 4
// 854.089 us; speedup vs baseline: 1.4338x; 1.1354x over previous
//
#include <hip/hip_runtime.h>
#include <hip/hip_bf16.h>

// GraphSAGE forward: proj -> [aggr -> gemm] x2 (+cls fused into gemm2)
// N=200000, E=3200000, IN_DIM=165, HID=64. All fp32.
//
// R12 design notes:
//  - post-mortem R11: XCD-pinned scatter was NULL (WRITE still 156MB).
//    Real cause is REUSE DISTANCE: a node's 16 edges are uniformly spread
//    over its bucket's 3.2MB plane, so each 64B csr line is evicted between
//    its ~16 writes (working set 4.9MB > 4MB L2) -> ~16x write amp.
//  - fix: hierarchical bucketing. A: 8-way bucket (unchanged, degree fused).
//    A2 (subsplit): split each bucket 25-way -> 1000-node sub-buckets,
//    pack edge as (dlocal<<18)|src in u32 plane (dlocal<1024, src<2^18).
//    B (subscatter): ONE block per sub-bucket; per-node cursors in LDS
//    (init from row_ptr, LDS atomics); csr window 64KB + plane 64KB fully
//    L2-resident -> each csr line written back once.
//  - global cursor array deleted.
//  - matmuls: 128-node blocks, 4x8 micro-tile (R10).

#define NNODES 200000
#define NEDGES 3200000
#define INDIM 165
#define HID 64

#define NR 8
#define RSIZE (NNODES / NR)   // 25000
#define CAP 416000            // per-bucket capacity (phase A)
#define NSUB 25               // sub-buckets per bucket
#define SUBSZ 1000            // nodes per sub-bucket
#define NSB (NR * NSUB)       // 200
#define CAP2 20480            // per-sub-bucket capacity (exp 16000, 35 sigma)
#define ACHUNK 4096

#define SCAN_T 256
#define SCAN_I 8
#define SCAN_CHUNK (SCAN_T * SCAN_I)

#define BKP 15            // proj K chunk: 165 = 11*15
#define BKG 16            // gemm K chunk: 64 = 4*16
#define NPB 128           // nodes per matmul block
#define XSTR 132          // 128 + 4 pad

typedef float f4 __attribute__((ext_vector_type(4)));

#define RELU4(v) { v.x=fmaxf(v.x,0.f); v.y=fmaxf(v.y,0.f); v.z=fmaxf(v.z,0.f); v.w=fmaxf(v.w,0.f); }

#define MT_FMA1(xv, wv0, wv1) \
  accA[0] += xv.x * wv0; accB[0] += xv.x * wv1; \
  accA[1] += xv.y * wv0; accB[1] += xv.y * wv1; \
  accA[2] += xv.z * wv0; accB[2] += xv.z * wv1; \
  accA[3] += xv.w * wv0; accB[3] += xv.w * wv1;

// ---------------- proj: h = relu(x @ Wp + bp) -----------------------------
__global__ __launch_bounds__(256, 4)
void proj_kernel(const float* __restrict__ x,
                 const float* __restrict__ Wp,
                 const float* __restrict__ bp,
                 float* __restrict__ h, int n) {
  __shared__ float x_s[BKP * XSTR];
  __shared__ float w_s[BKP * HID];
  int t = threadIdx.x;
  int tx = t & 7;
  int ng = t >> 3;
  int n0 = blockIdx.x * NPB;

  f4 b0 = ((const f4*)bp)[tx * 2];
  f4 b1 = ((const f4*)bp)[tx * 2 + 1];
  f4 accA[4], accB[4];
  #pragma unroll
  for (int i = 0; i < 4; ++i) { accA[i] = b0; accB[i] = b1; }

  for (int kc = 0; kc < INDIM / BKP; ++kc) {
    for (int i = t; i < NPB * BKP; i += 256) {
      int node = i / BKP, col = i - node * BKP;
      int gi = n0 + node; if (gi >= n) gi = n - 1;
      x_s[col * XSTR + node] = x[(size_t)gi * INDIM + kc * BKP + col];
    }
    if (t < BKP * HID / 4)
      ((f4*)w_s)[t] = ((const f4*)(Wp + kc * BKP * HID))[t];
    __syncthreads();
    #pragma unroll
    for (int k = 0; k < BKP; ++k) {
      f4 xv = *(const f4*)&x_s[k * XSTR + ng * 4];
      f4 wv0 = *(const f4*)&w_s[k * HID + tx * 8];
      f4 wv1 = *(const f4*)&w_s[k * HID + tx * 8 + 4];
      MT_FMA1(xv, wv0, wv1)
    }
    __syncthreads();
  }
  #pragma unroll
  for (int i = 0; i < 4; ++i) {
    int node = n0 + ng * 4 + i;
    if (node < n) {
      f4 a = accA[i], b = accB[i];
      RELU4(a) RELU4(b)
      *(f4*)&h[(size_t)node * HID + tx * 8] = a;
      *(f4*)&h[(size_t)node * HID + tx * 8 + 4] = b;
    }
  }
}

// ---------------- phase A: bucket edges by dst range + degree -------------
__global__ __launch_bounds__(256)
void bucket_kernel(const int* __restrict__ src, const int* __restrict__ dst,
                   int* __restrict__ gbase,
                   int* __restrict__ p_src, int* __restrict__ p_dst,
                   int* __restrict__ counts, int e) {
  __shared__ int wpart[4][NR];
  __shared__ int wbase[4][NR];
  __shared__ int bbase[NR];
  __shared__ int posm[NR][256];
  int t = threadIdx.x;
  int lane = t & 63, wid = t >> 6;
  int base = blockIdx.x * ACHUNK;

  int dreg[16];
  int c[NR];
  #pragma unroll
  for (int r = 0; r < NR; ++r) c[r] = 0;
  #pragma unroll
  for (int j = 0; j < 16; ++j) {
    int i = base + t + j * 256;
    int d = (i < e) ? __builtin_nontemporal_load(&dst[i]) : -1;
    dreg[j] = d;
    if (d >= 0) c[d / RSIZE]++;
  }
  int excl[NR];
  #pragma unroll
  for (int r = 0; r < NR; ++r) {
    int v = c[r];
    int incl = v;
    #pragma unroll
    for (int off = 1; off < 64; off <<= 1) {
      int y = __shfl_up(incl, off, 64);
      if (lane >= off) incl += y;
    }
    excl[r] = incl - v;
    if (lane == 63) wpart[wid][r] = incl;
  }
  __syncthreads();
  if (t < NR) {
    int s0 = wpart[0][t], s1 = wpart[1][t], s2 = wpart[2][t], s3 = wpart[3][t];
    int tot = s0 + s1 + s2 + s3;
    bbase[t] = atomicAdd(&gbase[t], tot);
    wbase[0][t] = 0; wbase[1][t] = s0; wbase[2][t] = s0 + s1; wbase[3][t] = s0 + s1 + s2;
  }
  __syncthreads();
  #pragma unroll
  for (int r = 0; r < NR; ++r)
    posm[r][t] = r * CAP + bbase[r] + wbase[wid][r] + excl[r];
  #pragma unroll
  for (int j = 0; j < 16; ++j) {
    int d = dreg[j];
    if (d >= 0) {
      int s = __builtin_nontemporal_load(&src[base + t + j * 256]);
      int r = d / RSIZE;
      int p = posm[r][t]++;
      p_dst[p] = d;
      p_src[p] = s;
      atomicAdd(&counts[d], 1);   // fused degree histogram
    }
  }
}

// ---------------- phase A2: split each bucket into 25 sub-buckets ---------
// Packs edge as (dlocal<<18)|src into u32 plane p2 (dlocal<1024, src<2^18).
__global__ __launch_bounds__(256)
void subsplit_kernel(const int* __restrict__ gbase,
                     const int* __restrict__ p_src, const int* __restrict__ p_dst,
                     int* __restrict__ gbase2, unsigned int* __restrict__ p2) {
  __shared__ int wpart[4][NSUB];
  __shared__ int wbase[4][NSUB];
  __shared__ int bbase[NSUB];
  __shared__ int posm[NSUB][256];
  int r = blockIdx.x & (NR - 1);
  int chunk = blockIdx.x >> 3;
  int n_r = gbase[r];
  int base = chunk * ACHUNK;
  if (base >= n_r) return;
  int end = min(base + ACHUNK, n_r);
  int t = threadIdx.x;
  int lane = t & 63, wid = t >> 6;
  const int* pd = p_dst + (size_t)r * CAP;
  const int* ps = p_src + (size_t)r * CAP;

  int dreg[16];
  int c[NSUB];
  #pragma unroll
  for (int s2 = 0; s2 < NSUB; ++s2) c[s2] = 0;
  #pragma unroll
  for (int j = 0; j < 16; ++j) {
    int i = base + t + j * 256;
    int d = (i < end) ? __builtin_nontemporal_load(&pd[i]) : -1;
    dreg[j] = d;
    // explicit unrolled compare-add: keeps c[] in registers (rule #20)
    int sub = (d >= 0) ? (unsigned)(d - r * RSIZE) / SUBSZ : -1;
    #pragma unroll
    for (int s2 = 0; s2 < NSUB; ++s2) c[s2] += (sub == s2);
  }
  int excl[NSUB];
  #pragma unroll
  for (int s2 = 0; s2 < NSUB; ++s2) {
    int v = c[s2];
    int incl = v;
    #pragma unroll
    for (int off = 1; off < 64; off <<= 1) {
      int y = __shfl_up(incl, off, 64);
      if (lane >= off) incl += y;
    }
    excl[s2] = incl - v;
    if (lane == 63) wpart[wid][s2] = incl;
  }
  __syncthreads();
  for (int s2 = t; s2 < NSUB; s2 += 256) {
    int s0 = wpart[0][s2], s1 = wpart[1][s2], sB = wpart[2][s2], sC = wpart[3][s2];
    int tot = s0 + s1 + sB + sC;
    bbase[s2] = atomicAdd(&gbase2[r * NSUB + s2], tot);
    wbase[0][s2] = 0; wbase[1][s2] = s0; wbase[2][s2] = s0 + s1; wbase[3][s2] = s0 + s1 + sB;
  }
  __syncthreads();
  #pragma unroll
  for (int s2 = 0; s2 < NSUB; ++s2)
    posm[s2][t] = (r * NSUB + s2) * CAP2 + bbase[s2] + wbase[wid][s2] + excl[s2];
  #pragma unroll
  for (int j = 0; j < 16; ++j) {
    int d = dreg[j];
    if (d >= 0) {
      int i = base + t + j * 256;
      int s = __builtin_nontemporal_load(&ps[i]);
      int dl0 = d - r * RSIZE;
      int sub = (unsigned)dl0 / SUBSZ;
      int dlocal = dl0 - sub * SUBSZ;
      int p = posm[sub][t]++;
      p2[p] = ((unsigned)dlocal << 18) | (unsigned)s;
    }
  }
}

// ---------------- scan ----------------------------------------------------
__global__ void scan1_kernel(const int* __restrict__ counts, int* __restrict__ row_ptr,
                             int* __restrict__ bsums, int n) {
  __shared__ int lds[SCAN_T];
  int b = blockIdx.x, t = threadIdx.x;
  int base = b * SCAN_CHUNK + t * SCAN_I;
  int v[SCAN_I];
  int s = 0;
  #pragma unroll
  for (int i = 0; i < SCAN_I; ++i) {
    int idx = base + i;
    v[i] = (idx < n) ? counts[idx] : 0;
    s += v[i];
  }
  lds[t] = s;
  __syncthreads();
  for (int off = 1; off < SCAN_T; off <<= 1) {
    int y = (t >= off) ? lds[t - off] : 0;
    __syncthreads();
    lds[t] += y;
    __syncthreads();
  }
  int incl = lds[t];
  int run = incl - s;
  #pragma unroll
  for (int i = 0; i < SCAN_I; ++i) {
    int idx = base + i;
    if (idx < n) row_ptr[idx] = run;
    run += v[i];
  }
  if (t == SCAN_T - 1) bsums[b] = incl;
}

__global__ void scan2_kernel(int* __restrict__ bsums, int nb) {
  __shared__ int lds[SCAN_T];
  int t = threadIdx.x;
  int v = (t < nb) ? bsums[t] : 0;
  lds[t] = v;
  __syncthreads();
  for (int off = 1; off < SCAN_T; off <<= 1) {
    int y = (t >= off) ? lds[t - off] : 0;
    __syncthreads();
    lds[t] += y;
    __syncthreads();
  }
  if (t < nb) bsums[t] = lds[t] - v;
}

__global__ void scan3_kernel(int* __restrict__ row_ptr, const int* __restrict__ bsums,
                             int n, int e) {
  int i = blockIdx.x * blockDim.x + threadIdx.x;
  if (i < n) row_ptr[i] = row_ptr[i] + bsums[i / SCAN_CHUNK];
  if (i == n) row_ptr[n] = e;
}

// ---------------- phase B: per-sub-bucket scatter, LDS cursors ------------
// One block per sub-bucket. csr window (64KB) + plane (64KB) are L2
// resident; cursors in LDS -> each csr line written back once.
__global__ __launch_bounds__(512)
void subscatter_kernel(const int* __restrict__ gbase2,
                       const unsigned int* __restrict__ p2,
                       const int* __restrict__ row_ptr,
                       int* __restrict__ csr_src) {
  __shared__ int cur[SUBSZ];
  int sb = blockIdx.x;          // 0..NSB-1
  int n = gbase2[sb];
  int dst0 = (sb / NSUB) * RSIZE + (sb % NSUB) * SUBSZ;
  int t = threadIdx.x;
  for (int i = t; i < SUBSZ; i += 512) cur[i] = row_ptr[dst0 + i];
  __syncthreads();
  const unsigned int* pl = p2 + (size_t)sb * CAP2;
  for (int i = t; i < n; i += 512) {
    unsigned int w = __builtin_nontemporal_load(&pl[i]);
    int dl = (int)(w >> 18);
    int s = (int)(w & 0x3FFFFu);
    int pos = atomicAdd(&cur[dl], 1);
    csr_src[pos] = s;
  }
}

// ---------------- mean aggregation (pull, CSR) ----------------------------
__global__ void aggr_kernel(const float* __restrict__ hin,
                            const int* __restrict__ row_ptr,
                            const int* __restrict__ csr_src,
                            float* __restrict__ aggr, int n) {
  int lane = threadIdx.x & 63;
  int grp = lane >> 4, sub = lane & 15;
  int node = (blockIdx.x * blockDim.x + threadIdx.x) >> 6;
  if (node >= n) return;
  int r0 = row_ptr[node], r1 = row_ptr[node + 1];
  f4 acc0 = {0.f, 0.f, 0.f, 0.f}, acc1 = {0.f, 0.f, 0.f, 0.f};
  int p = r0;
  for (; p + 8 <= r1; p += 8) {
    int i0 = csr_src[p + grp];
    int i1 = csr_src[p + 4 + grp];
    f4 v0 = *((const f4*)(hin + (size_t)i0 * HID) + sub);
    f4 v1 = *((const f4*)(hin + (size_t)i1 * HID) + sub);
    acc0 += v0;
    acc1 += v1;
  }
  if (p + 4 <= r1) {
    int i0 = csr_src[p + grp];
    acc0 += *((const f4*)(hin + (size_t)i0 * HID) + sub);
    p += 4;
  }
  int rem = r1 - p;
  if (grp < rem) {
    int i0 = csr_src[p + grp];
    acc1 += *((const f4*)(hin + (size_t)i0 * HID) + sub);
  }
  acc0 += acc1;
  #pragma unroll
  for (int c = 0; c < 4; ++c) {
    float v = acc0[c];
    v += __shfl_xor(v, 16, 64);
    v += __shfl_xor(v, 32, 64);
    acc0[c] = v;
  }
  int deg = r1 - r0;
  float rdeg = 1.f / (float)(deg > 1 ? deg : 1);
  if (grp == 0) {
    f4 o = acc0 * rdeg;
    *((f4*)(aggr + (size_t)node * HID) + sub) = o;
  }
}

// ---------------- gemm: hout = relu(aggr@Wl + bl + hin@Wr) ---------------
#define GEMM_BODY(aggrp, hinp) \
  for (int kc = 0; kc < HID / BKG; ++kc) { \
    for (int i = t; i < NPB * BKG; i += 256) { \
      int node = i >> 4, k = i & 15; \
      int gi = n0 + node; if (gi >= n) gi = n - 1; \
      a_s[k * XSTR + node] = aggrp[(size_t)gi * HID + kc * BKG + k]; \
      h_s[k * XSTR + node] = hinp[(size_t)gi * HID + kc * BKG + k]; \
    } \
    ((f4*)wl_s)[t] = ((const f4*)(Wl + kc * BKG * HID))[t]; \
    ((f4*)wr_s)[t] = ((const f4*)(Wr + kc * BKG * HID))[t]; \
    __syncthreads(); \
    _Pragma("unroll") \
    for (int k = 0; k < BKG; ++k) { \
      f4 av = *(const f4*)&a_s[k * XSTR + ng * 4]; \
      f4 hv = *(const f4*)&h_s[k * XSTR + ng * 4]; \
      f4 wl0 = *(const f4*)&wl_s[k * HID + tx * 8]; \
      f4 wl1 = *(const f4*)&wl_s[k * HID + tx * 8 + 4]; \
      f4 wr0 = *(const f4*)&wr_s[k * HID + tx * 8]; \
      f4 wr1 = *(const f4*)&wr_s[k * HID + tx * 8 + 4]; \
      accA[0] += av.x * wl0 + hv.x * wr0;  accB[0] += av.x * wl1 + hv.x * wr1; \
      accA[1] += av.y * wl0 + hv.y * wr0;  accB[1] += av.y * wl1 + hv.y * wr1; \
      accA[2] += av.z * wl0 + hv.z * wr0;  accB[2] += av.z * wl1 + hv.z * wr1; \
      accA[3] += av.w * wl0 + hv.w * wr0;  accB[3] += av.w * wl1 + hv.w * wr1; \
    } \
    __syncthreads(); \
  }

__global__ __launch_bounds__(256, 4)
void gemm_kernel(const float* __restrict__ aggr,
                 const float* hin,
                 const float* __restrict__ Wl, const float* __restrict__ bl,
                 const float* __restrict__ Wr,
                 float* hout, int n) {
  __shared__ float a_s[BKG * XSTR];
  __shared__ float h_s[BKG * XSTR];
  __shared__ float wl_s[BKG * HID];
  __shared__ float wr_s[BKG * HID];
  int t = threadIdx.x;
  int tx = t & 7;
  int ng = t >> 3;
  int n0 = blockIdx.x * NPB;

  f4 b0 = ((const f4*)bl)[tx * 2];
  f4 b1 = ((const f4*)bl)[tx * 2 + 1];
  f4 accA[4], accB[4];
  #pragma unroll
  for (int i = 0; i < 4; ++i) { accA[i] = b0; accB[i] = b1; }

  GEMM_BODY(aggr, hin)

  #pragma unroll
  for (int i = 0; i < 4; ++i) {
    int node = n0 + ng * 4 + i;
    if (node < n) {
      f4 a = accA[i], b = accB[i];
      RELU4(a) RELU4(b)
      *(f4*)&hout[(size_t)node * HID + tx * 8] = a;
      *(f4*)&hout[(size_t)node * HID + tx * 8 + 4] = b;
    }
  }
}

// ---------------- gemm2 + cls fused ---------------------------------------
__global__ __launch_bounds__(256, 4)
void gemm_cls_kernel(const float* __restrict__ aggr,
                     const float* __restrict__ hin,
                     const float* __restrict__ Wl, const float* __restrict__ bl,
                     const float* __restrict__ Wr,
                     const float* __restrict__ Wc, const float* __restrict__ bc,
                     float* __restrict__ out, int n) {
  __shared__ float a_s[BKG * XSTR];
  __shared__ float h_s[BKG * XSTR];
  __shared__ float wl_s[BKG * HID];
  __shared__ float wr_s[BKG * HID];
  int t = threadIdx.x;
  int tx = t & 7;
  int ng = t >> 3;
  int n0 = blockIdx.x * NPB;

  f4 b0 = ((const f4*)bl)[tx * 2];
  f4 b1 = ((const f4*)bl)[tx * 2 + 1];
  f4 accA[4], accB[4];
  #pragma unroll
  for (int i = 0; i < 4; ++i) { accA[i] = b0; accB[i] = b1; }

  GEMM_BODY(aggr, hin)

  f4 wc0 = ((const f4*)Wc)[tx * 2];
  f4 wc1 = ((const f4*)Wc)[tx * 2 + 1];
  float bcv = bc[0];
  #pragma unroll
  for (int i = 0; i < 4; ++i) {
    f4 a = accA[i], b = accB[i];
    RELU4(a) RELU4(b)
    float s = a.x * wc0.x + a.y * wc0.y + a.z * wc0.z + a.w * wc0.w
            + b.x * wc1.x + b.y * wc1.y + b.z * wc1.z + b.w * wc1.w;
    s += __shfl_xor(s, 1, 64);
    s += __shfl_xor(s, 2, 64);
    s += __shfl_xor(s, 4, 64);
    int node = n0 + ng * 4 + i;
    if (tx == 0 && node < n) out[node] = s + bcv;
  }
}

extern "C" void kernel_launch(void* const* d_in, const int* in_sizes, int n_in,
                              void* d_out, int out_size, void* d_ws, size_t ws_size,
                              hipStream_t stream) {
  const float* x   = (const float*)d_in[0];
  const int*   ei  = (const int*)d_in[1];
  const float* Wp  = (const float*)d_in[2];
  const float* bp  = (const float*)d_in[3];
  const float* W1l = (const float*)d_in[4];
  const float* b1l = (const float*)d_in[5];
  const float* W1r = (const float*)d_in[6];
  const float* W2l = (const float*)d_in[7];
  const float* b2l = (const float*)d_in[8];
  const float* W2r = (const float*)d_in[9];
  const float* Wc  = (const float*)d_in[10];
  const float* bc  = (const float*)d_in[11];
  float* out = (float*)d_out;

  const int N = NNODES, E = NEDGES;
  const int* src = ei;
  const int* dst = ei + E;

  char* ws = (char*)d_ws;
  float* h       = (float*)(ws + 0);          // 51,200,000 B
  float* aggr    = (float*)(ws + 51200000);   // 51,200,000 B
  // aliases inside aggr (dead until after subscatter):
  int*   p_src   = (int*)  (ws + 51200000);   // NR*CAP*4 = 13,312,000
  int*   p_dst   = p_src + (size_t)NR * CAP;  // +13,312,000 -> ends 77,824,000
  unsigned int* p2 = (unsigned int*)(ws + 77824000); // NSB*CAP2*4 = 16,384,000 -> ends 94,208,000
  int*   counts  = (int*)  (ws + 102400000);  // 800,000
  int*   gbase   = (int*)  (ws + 103200000);  // 32
  int*   gbase2  = (int*)  (ws + 103200032);  // 800
  int*   row_ptr = (int*)  (ws + 103200832);  // 800,004
  int*   csr_src = (int*)  (ws + 104000896);  // 12,800,000
  int*   bsums   = (int*)  (ws + 116800896);  // ~400

  // zero counts + gbase + gbase2 in one contiguous memset
  hipMemsetAsync(counts, 0, (size_t)N * 4 + 32 + NSB * 4, stream);

  int mgrid = (N + NPB - 1) / NPB;                     // 1563
  proj_kernel<<<mgrid, 256, 0, stream>>>(x, Wp, bp, h, N);

  int nchunksA = (E + ACHUNK - 1) / ACHUNK;            // 782
  bucket_kernel<<<nchunksA, 256, 0, stream>>>(src, dst, gbase, p_src, p_dst, counts, E);

  int nchunksB = (CAP + ACHUNK - 1) / ACHUNK;          // 102
  subsplit_kernel<<<nchunksB * NR, 256, 0, stream>>>(gbase, p_src, p_dst, gbase2, p2);

  int nb = (N + SCAN_CHUNK - 1) / SCAN_CHUNK;
  scan1_kernel<<<nb, SCAN_T, 0, stream>>>(counts, row_ptr, bsums, N);
  scan2_kernel<<<1, SCAN_T, 0, stream>>>(bsums, nb);
  scan3_kernel<<<(N + 256) / 256, 256, 0, stream>>>(row_ptr, bsums, N, E);

  subscatter_kernel<<<NSB, 512, 0, stream>>>(gbase2, p2, row_ptr, csr_src);

  aggr_kernel<<<(N + 3) / 4, 256, 0, stream>>>(h, row_ptr, csr_src, aggr, N);
  gemm_kernel<<<mgrid, 256, 0, stream>>>(aggr, h, W1l, b1l, W1r, h, N);

  aggr_kernel<<<(N + 3) / 4, 256, 0, stream>>>(h, row_ptr, csr_src, aggr, N);
  gemm_cls_kernel<<<mgrid, 256, 0, stream>>>(aggr, h, W2l, b2l, W2r, Wc, bc, out, N);
}

// Round 5
// 777.940 us; speedup vs baseline: 1.5741x; 1.0979x over previous
//
#include <hip/hip_runtime.h>
#include <hip/hip_bf16.h>

// GraphSAGE forward: proj -> [aggr -> gemm] x2 (+cls fused into gemm2)
// N=200000, E=3200000, IN_DIM=165, HID=64. All fp32.
//
// R13 design notes:
//  - post-mortem R12: bucket_kernel WRITE=262MB; the fused degree histogram
//    (atomicAdd to 4096 RANDOM counts lines per block, 16MB dirty set/XCD)
//    caused ~205MB of partial-line writebacks. The R10 lesson generalizes:
//    scattered read-modify-write MUST be confined to an L2-resident window.
//  - fix: degree histogram DELETED. subscatter computes row_ptr itself:
//    each block recomputes the 200-entry gbase2 prefix in LDS (~1us),
//    histograms its 1000-node window in LDS from the L2-resident plane,
//    block-scans it, writes row_ptr + cursors. counts/scan1/2/3 removed.
//  - pipeline: bucket(8-way) -> subsplit(25-way, packed u32) ->
//    subscatter(histogram+scan+scatter, all LDS) -> aggr -> gemm.
//  - matmuls: 128-node blocks, 4x8 micro-tile (R10).

#define NNODES 200000
#define NEDGES 3200000
#define INDIM 165
#define HID 64

#define NR 8
#define RSIZE (NNODES / NR)   // 25000
#define CAP 416000            // per-bucket capacity (phase A)
#define NSUB 25               // sub-buckets per bucket
#define SUBSZ 1000            // nodes per sub-bucket
#define NSB (NR * NSUB)       // 200
#define CAP2 20480            // per-sub-bucket capacity (exp 16000, 35 sigma)
#define ACHUNK 4096

#define BKP 15            // proj K chunk: 165 = 11*15
#define BKG 16            // gemm K chunk: 64 = 4*16
#define NPB 128           // nodes per matmul block
#define XSTR 132          // 128 + 4 pad

typedef float f4 __attribute__((ext_vector_type(4)));

#define RELU4(v) { v.x=fmaxf(v.x,0.f); v.y=fmaxf(v.y,0.f); v.z=fmaxf(v.z,0.f); v.w=fmaxf(v.w,0.f); }

#define MT_FMA1(xv, wv0, wv1) \
  accA[0] += xv.x * wv0; accB[0] += xv.x * wv1; \
  accA[1] += xv.y * wv0; accB[1] += xv.y * wv1; \
  accA[2] += xv.z * wv0; accB[2] += xv.z * wv1; \
  accA[3] += xv.w * wv0; accB[3] += xv.w * wv1;

// ---------------- proj: h = relu(x @ Wp + bp) -----------------------------
__global__ __launch_bounds__(256, 4)
void proj_kernel(const float* __restrict__ x,
                 const float* __restrict__ Wp,
                 const float* __restrict__ bp,
                 float* __restrict__ h, int n) {
  __shared__ float x_s[BKP * XSTR];
  __shared__ float w_s[BKP * HID];
  int t = threadIdx.x;
  int tx = t & 7;
  int ng = t >> 3;
  int n0 = blockIdx.x * NPB;

  f4 b0 = ((const f4*)bp)[tx * 2];
  f4 b1 = ((const f4*)bp)[tx * 2 + 1];
  f4 accA[4], accB[4];
  #pragma unroll
  for (int i = 0; i < 4; ++i) { accA[i] = b0; accB[i] = b1; }

  for (int kc = 0; kc < INDIM / BKP; ++kc) {
    for (int i = t; i < NPB * BKP; i += 256) {
      int node = i / BKP, col = i - node * BKP;
      int gi = n0 + node; if (gi >= n) gi = n - 1;
      x_s[col * XSTR + node] = x[(size_t)gi * INDIM + kc * BKP + col];
    }
    if (t < BKP * HID / 4)
      ((f4*)w_s)[t] = ((const f4*)(Wp + kc * BKP * HID))[t];
    __syncthreads();
    #pragma unroll
    for (int k = 0; k < BKP; ++k) {
      f4 xv = *(const f4*)&x_s[k * XSTR + ng * 4];
      f4 wv0 = *(const f4*)&w_s[k * HID + tx * 8];
      f4 wv1 = *(const f4*)&w_s[k * HID + tx * 8 + 4];
      MT_FMA1(xv, wv0, wv1)
    }
    __syncthreads();
  }
  #pragma unroll
  for (int i = 0; i < 4; ++i) {
    int node = n0 + ng * 4 + i;
    if (node < n) {
      f4 a = accA[i], b = accB[i];
      RELU4(a) RELU4(b)
      *(f4*)&h[(size_t)node * HID + tx * 8] = a;
      *(f4*)&h[(size_t)node * HID + tx * 8 + 4] = b;
    }
  }
}

// ---------------- phase A: bucket edges by dst range ----------------------
__global__ __launch_bounds__(256)
void bucket_kernel(const int* __restrict__ src, const int* __restrict__ dst,
                   int* __restrict__ gbase,
                   int* __restrict__ p_src, int* __restrict__ p_dst, int e) {
  __shared__ int wpart[4][NR];
  __shared__ int wbase[4][NR];
  __shared__ int bbase[NR];
  __shared__ int posm[NR][256];
  int t = threadIdx.x;
  int lane = t & 63, wid = t >> 6;
  int base = blockIdx.x * ACHUNK;

  int dreg[16];
  int c[NR];
  #pragma unroll
  for (int r = 0; r < NR; ++r) c[r] = 0;
  #pragma unroll
  for (int j = 0; j < 16; ++j) {
    int i = base + t + j * 256;
    int d = (i < e) ? __builtin_nontemporal_load(&dst[i]) : -1;
    dreg[j] = d;
    if (d >= 0) c[d / RSIZE]++;
  }
  int excl[NR];
  #pragma unroll
  for (int r = 0; r < NR; ++r) {
    int v = c[r];
    int incl = v;
    #pragma unroll
    for (int off = 1; off < 64; off <<= 1) {
      int y = __shfl_up(incl, off, 64);
      if (lane >= off) incl += y;
    }
    excl[r] = incl - v;
    if (lane == 63) wpart[wid][r] = incl;
  }
  __syncthreads();
  if (t < NR) {
    int s0 = wpart[0][t], s1 = wpart[1][t], s2 = wpart[2][t], s3 = wpart[3][t];
    int tot = s0 + s1 + s2 + s3;
    bbase[t] = atomicAdd(&gbase[t], tot);
    wbase[0][t] = 0; wbase[1][t] = s0; wbase[2][t] = s0 + s1; wbase[3][t] = s0 + s1 + s2;
  }
  __syncthreads();
  #pragma unroll
  for (int r = 0; r < NR; ++r)
    posm[r][t] = r * CAP + bbase[r] + wbase[wid][r] + excl[r];
  #pragma unroll
  for (int j = 0; j < 16; ++j) {
    int d = dreg[j];
    if (d >= 0) {
      int s = __builtin_nontemporal_load(&src[base + t + j * 256]);
      int r = d / RSIZE;
      int p = posm[r][t]++;
      p_dst[p] = d;
      p_src[p] = s;
    }
  }
}

// ---------------- phase A2: split each bucket into 25 sub-buckets ---------
// Packs edge as (dlocal<<18)|src into u32 plane p2 (dlocal<1024, src<2^18).
__global__ __launch_bounds__(256)
void subsplit_kernel(const int* __restrict__ gbase,
                     const int* __restrict__ p_src, const int* __restrict__ p_dst,
                     int* __restrict__ gbase2, unsigned int* __restrict__ p2) {
  __shared__ int wpart[4][NSUB];
  __shared__ int wbase[4][NSUB];
  __shared__ int bbase[NSUB];
  __shared__ int posm[NSUB][256];
  int r = blockIdx.x & (NR - 1);
  int chunk = blockIdx.x >> 3;
  int n_r = gbase[r];
  int base = chunk * ACHUNK;
  if (base >= n_r) return;
  int end = min(base + ACHUNK, n_r);
  int t = threadIdx.x;
  int lane = t & 63, wid = t >> 6;
  const int* pd = p_dst + (size_t)r * CAP;
  const int* ps = p_src + (size_t)r * CAP;

  int dreg[16];
  int c[NSUB];
  #pragma unroll
  for (int s2 = 0; s2 < NSUB; ++s2) c[s2] = 0;
  #pragma unroll
  for (int j = 0; j < 16; ++j) {
    int i = base + t + j * 256;
    int d = (i < end) ? __builtin_nontemporal_load(&pd[i]) : -1;
    dreg[j] = d;
    int sub = (d >= 0) ? (unsigned)(d - r * RSIZE) / SUBSZ : -1;
    #pragma unroll
    for (int s2 = 0; s2 < NSUB; ++s2) c[s2] += (sub == s2);
  }
  int excl[NSUB];
  #pragma unroll
  for (int s2 = 0; s2 < NSUB; ++s2) {
    int v = c[s2];
    int incl = v;
    #pragma unroll
    for (int off = 1; off < 64; off <<= 1) {
      int y = __shfl_up(incl, off, 64);
      if (lane >= off) incl += y;
    }
    excl[s2] = incl - v;
    if (lane == 63) wpart[wid][s2] = incl;
  }
  __syncthreads();
  for (int s2 = t; s2 < NSUB; s2 += 256) {
    int s0 = wpart[0][s2], s1 = wpart[1][s2], sB = wpart[2][s2], sC = wpart[3][s2];
    int tot = s0 + s1 + sB + sC;
    bbase[s2] = atomicAdd(&gbase2[r * NSUB + s2], tot);
    wbase[0][s2] = 0; wbase[1][s2] = s0; wbase[2][s2] = s0 + s1; wbase[3][s2] = s0 + s1 + sB;
  }
  __syncthreads();
  #pragma unroll
  for (int s2 = 0; s2 < NSUB; ++s2)
    posm[s2][t] = (r * NSUB + s2) * CAP2 + bbase[s2] + wbase[wid][s2] + excl[s2];
  #pragma unroll
  for (int j = 0; j < 16; ++j) {
    int d = dreg[j];
    if (d >= 0) {
      int i = base + t + j * 256;
      int s = __builtin_nontemporal_load(&ps[i]);
      int dl0 = d - r * RSIZE;
      int sub = (unsigned)dl0 / SUBSZ;
      int dlocal = dl0 - sub * SUBSZ;
      int p = posm[sub][t]++;
      p2[p] = ((unsigned)dlocal << 18) | (unsigned)s;
    }
  }
}

// ---------------- phase B: subscatter -------------------------------------
// One block per sub-bucket. Recomputes the 200-entry gbase2 prefix in LDS,
// histograms its 1000-node window (L2-resident plane), block-scans it,
// writes row_ptr AND scatters csr_src -- everything through LDS, each csr
// line written back once. No global counts / cursor arrays.
__global__ __launch_bounds__(512)
void subscatter_kernel(const int* __restrict__ gbase2,
                       const unsigned int* __restrict__ p2,
                       int* __restrict__ row_ptr,
                       int* __restrict__ csr_src) {
  __shared__ int hist[SUBSZ];   // histogram -> cursors
  __shared__ int sc[256];       // sub-bucket prefix scan
  __shared__ int wsum[8];
  int sb = blockIdx.x;
  int t = threadIdx.x;
  int lane = t & 63, wid = t >> 6;

  // exclusive prefix of gbase2[0..sb) (200 entries, LDS log-scan)
  if (t < 256) sc[t] = (t < NSB) ? gbase2[t] : 0;
  __syncthreads();
  for (int off = 1; off < 256; off <<= 1) {
    int y = 0;
    if (t < 256 && t >= off) y = sc[t - off];
    __syncthreads();
    if (t < 256) sc[t] += y;
    __syncthreads();
  }
  int n = gbase2[sb];
  int base0 = sc[sb] - n;       // exclusive prefix = global edge offset

  for (int i = t; i < SUBSZ; i += 512) hist[i] = 0;
  __syncthreads();

  const unsigned int* pl = p2 + (size_t)sb * CAP2;
  for (int i = t; i < n; i += 512)
    atomicAdd(&hist[pl[i] >> 18], 1);
  __syncthreads();

  // block scan of hist[0..SUBSZ): 2 entries/thread
  int e0 = t * 2, e1 = e0 + 1;
  int v0 = (e0 < SUBSZ) ? hist[e0] : 0;
  int v1 = (e1 < SUBSZ) ? hist[e1] : 0;
  int s = v0 + v1;
  int incl = s;
  #pragma unroll
  for (int off = 1; off < 64; off <<= 1) {
    int y = __shfl_up(incl, off, 64);
    if (lane >= off) incl += y;
  }
  if (lane == 63) wsum[wid] = incl;
  __syncthreads();
  if (t == 0) {
    int run = 0;
    #pragma unroll
    for (int w = 0; w < 8; ++w) { int v = wsum[w]; wsum[w] = run; run += v; }
  }
  __syncthreads();   // also guarantees all hist reads (v0/v1) are done
  int b0 = base0 + (incl - s) + wsum[wid];
  int dst0 = sb * SUBSZ;
  if (e0 < SUBSZ) { hist[e0] = b0;      row_ptr[dst0 + e0] = b0; }
  if (e1 < SUBSZ) { hist[e1] = b0 + v0; row_ptr[dst0 + e1] = b0 + v0; }
  if (sb == NSB - 1 && t == 0) row_ptr[NNODES] = NEDGES;
  __syncthreads();

  for (int i = t; i < n; i += 512) {
    unsigned int w = pl[i];                 // L2 hit (just read)
    int dl = (int)(w >> 18);
    int srcv = (int)(w & 0x3FFFFu);
    int pos = atomicAdd(&hist[dl], 1);
    csr_src[pos] = srcv;
  }
}

// ---------------- mean aggregation (pull, CSR) ----------------------------
__global__ void aggr_kernel(const float* __restrict__ hin,
                            const int* __restrict__ row_ptr,
                            const int* __restrict__ csr_src,
                            float* __restrict__ aggr, int n) {
  int lane = threadIdx.x & 63;
  int grp = lane >> 4, sub = lane & 15;
  int node = (blockIdx.x * blockDim.x + threadIdx.x) >> 6;
  if (node >= n) return;
  int r0 = row_ptr[node], r1 = row_ptr[node + 1];
  f4 acc0 = {0.f, 0.f, 0.f, 0.f}, acc1 = {0.f, 0.f, 0.f, 0.f};
  int p = r0;
  for (; p + 8 <= r1; p += 8) {
    int i0 = csr_src[p + grp];
    int i1 = csr_src[p + 4 + grp];
    f4 v0 = *((const f4*)(hin + (size_t)i0 * HID) + sub);
    f4 v1 = *((const f4*)(hin + (size_t)i1 * HID) + sub);
    acc0 += v0;
    acc1 += v1;
  }
  if (p + 4 <= r1) {
    int i0 = csr_src[p + grp];
    acc0 += *((const f4*)(hin + (size_t)i0 * HID) + sub);
    p += 4;
  }
  int rem = r1 - p;
  if (grp < rem) {
    int i0 = csr_src[p + grp];
    acc1 += *((const f4*)(hin + (size_t)i0 * HID) + sub);
  }
  acc0 += acc1;
  #pragma unroll
  for (int c = 0; c < 4; ++c) {
    float v = acc0[c];
    v += __shfl_xor(v, 16, 64);
    v += __shfl_xor(v, 32, 64);
    acc0[c] = v;
  }
  int deg = r1 - r0;
  float rdeg = 1.f / (float)(deg > 1 ? deg : 1);
  if (grp == 0) {
    f4 o = acc0 * rdeg;
    *((f4*)(aggr + (size_t)node * HID) + sub) = o;
  }
}

// ---------------- gemm: hout = relu(aggr@Wl + bl + hin@Wr) ---------------
#define GEMM_BODY(aggrp, hinp) \
  for (int kc = 0; kc < HID / BKG; ++kc) { \
    for (int i = t; i < NPB * BKG; i += 256) { \
      int node = i >> 4, k = i & 15; \
      int gi = n0 + node; if (gi >= n) gi = n - 1; \
      a_s[k * XSTR + node] = aggrp[(size_t)gi * HID + kc * BKG + k]; \
      h_s[k * XSTR + node] = hinp[(size_t)gi * HID + kc * BKG + k]; \
    } \
    ((f4*)wl_s)[t] = ((const f4*)(Wl + kc * BKG * HID))[t]; \
    ((f4*)wr_s)[t] = ((const f4*)(Wr + kc * BKG * HID))[t]; \
    __syncthreads(); \
    _Pragma("unroll") \
    for (int k = 0; k < BKG; ++k) { \
      f4 av = *(const f4*)&a_s[k * XSTR + ng * 4]; \
      f4 hv = *(const f4*)&h_s[k * XSTR + ng * 4]; \
      f4 wl0 = *(const f4*)&wl_s[k * HID + tx * 8]; \
      f4 wl1 = *(const f4*)&wl_s[k * HID + tx * 8 + 4]; \
      f4 wr0 = *(const f4*)&wr_s[k * HID + tx * 8]; \
      f4 wr1 = *(const f4*)&wr_s[k * HID + tx * 8 + 4]; \
      accA[0] += av.x * wl0 + hv.x * wr0;  accB[0] += av.x * wl1 + hv.x * wr1; \
      accA[1] += av.y * wl0 + hv.y * wr0;  accB[1] += av.y * wl1 + hv.y * wr1; \
      accA[2] += av.z * wl0 + hv.z * wr0;  accB[2] += av.z * wl1 + hv.z * wr1; \
      accA[3] += av.w * wl0 + hv.w * wr0;  accB[3] += av.w * wl1 + hv.w * wr1; \
    } \
    __syncthreads(); \
  }

__global__ __launch_bounds__(256, 4)
void gemm_kernel(const float* __restrict__ aggr,
                 const float* hin,
                 const float* __restrict__ Wl, const float* __restrict__ bl,
                 const float* __restrict__ Wr,
                 float* hout, int n) {
  __shared__ float a_s[BKG * XSTR];
  __shared__ float h_s[BKG * XSTR];
  __shared__ float wl_s[BKG * HID];
  __shared__ float wr_s[BKG * HID];
  int t = threadIdx.x;
  int tx = t & 7;
  int ng = t >> 3;
  int n0 = blockIdx.x * NPB;

  f4 b0 = ((const f4*)bl)[tx * 2];
  f4 b1 = ((const f4*)bl)[tx * 2 + 1];
  f4 accA[4], accB[4];
  #pragma unroll
  for (int i = 0; i < 4; ++i) { accA[i] = b0; accB[i] = b1; }

  GEMM_BODY(aggr, hin)

  #pragma unroll
  for (int i = 0; i < 4; ++i) {
    int node = n0 + ng * 4 + i;
    if (node < n) {
      f4 a = accA[i], b = accB[i];
      RELU4(a) RELU4(b)
      *(f4*)&hout[(size_t)node * HID + tx * 8] = a;
      *(f4*)&hout[(size_t)node * HID + tx * 8 + 4] = b;
    }
  }
}

// ---------------- gemm2 + cls fused ---------------------------------------
__global__ __launch_bounds__(256, 4)
void gemm_cls_kernel(const float* __restrict__ aggr,
                     const float* __restrict__ hin,
                     const float* __restrict__ Wl, const float* __restrict__ bl,
                     const float* __restrict__ Wr,
                     const float* __restrict__ Wc, const float* __restrict__ bc,
                     float* __restrict__ out, int n) {
  __shared__ float a_s[BKG * XSTR];
  __shared__ float h_s[BKG * XSTR];
  __shared__ float wl_s[BKG * HID];
  __shared__ float wr_s[BKG * HID];
  int t = threadIdx.x;
  int tx = t & 7;
  int ng = t >> 3;
  int n0 = blockIdx.x * NPB;

  f4 b0 = ((const f4*)bl)[tx * 2];
  f4 b1 = ((const f4*)bl)[tx * 2 + 1];
  f4 accA[4], accB[4];
  #pragma unroll
  for (int i = 0; i < 4; ++i) { accA[i] = b0; accB[i] = b1; }

  GEMM_BODY(aggr, hin)

  f4 wc0 = ((const f4*)Wc)[tx * 2];
  f4 wc1 = ((const f4*)Wc)[tx * 2 + 1];
  float bcv = bc[0];
  #pragma unroll
  for (int i = 0; i < 4; ++i) {
    f4 a = accA[i], b = accB[i];
    RELU4(a) RELU4(b)
    float s = a.x * wc0.x + a.y * wc0.y + a.z * wc0.z + a.w * wc0.w
            + b.x * wc1.x + b.y * wc1.y + b.z * wc1.z + b.w * wc1.w;
    s += __shfl_xor(s, 1, 64);
    s += __shfl_xor(s, 2, 64);
    s += __shfl_xor(s, 4, 64);
    int node = n0 + ng * 4 + i;
    if (tx == 0 && node < n) out[node] = s + bcv;
  }
}

extern "C" void kernel_launch(void* const* d_in, const int* in_sizes, int n_in,
                              void* d_out, int out_size, void* d_ws, size_t ws_size,
                              hipStream_t stream) {
  const float* x   = (const float*)d_in[0];
  const int*   ei  = (const int*)d_in[1];
  const float* Wp  = (const float*)d_in[2];
  const float* bp  = (const float*)d_in[3];
  const float* W1l = (const float*)d_in[4];
  const float* b1l = (const float*)d_in[5];
  const float* W1r = (const float*)d_in[6];
  const float* W2l = (const float*)d_in[7];
  const float* b2l = (const float*)d_in[8];
  const float* W2r = (const float*)d_in[9];
  const float* Wc  = (const float*)d_in[10];
  const float* bc  = (const float*)d_in[11];
  float* out = (float*)d_out;

  const int N = NNODES, E = NEDGES;
  const int* src = ei;
  const int* dst = ei + E;

  char* ws = (char*)d_ws;
  float* h       = (float*)(ws + 0);          // 51,200,000 B
  float* aggr    = (float*)(ws + 51200000);   // 51,200,000 B
  // aliases inside aggr (dead until after subscatter):
  int*   p_src   = (int*)  (ws + 51200000);   // NR*CAP*4 = 13,312,000
  int*   p_dst   = p_src + (size_t)NR * CAP;  // +13,312,000 -> ends 77,824,000
  unsigned int* p2 = (unsigned int*)(ws + 77824000); // NSB*CAP2*4 = 16,384,000
  int*   gbase   = (int*)  (ws + 102400000);  // 32 B
  int*   gbase2  = (int*)  (ws + 102400032);  // 800 B
  int*   row_ptr = (int*)  (ws + 102400832);  // 800,004 B
  int*   csr_src = (int*)  (ws + 103200896);  // 12,800,000 B

  // zero gbase + gbase2 (contiguous, 832 B)
  hipMemsetAsync(gbase, 0, 832, stream);

  int mgrid = (N + NPB - 1) / NPB;                     // 1563
  proj_kernel<<<mgrid, 256, 0, stream>>>(x, Wp, bp, h, N);

  int nchunksA = (E + ACHUNK - 1) / ACHUNK;            // 782
  bucket_kernel<<<nchunksA, 256, 0, stream>>>(src, dst, gbase, p_src, p_dst, E);

  int nchunksB = (CAP + ACHUNK - 1) / ACHUNK;          // 102
  subsplit_kernel<<<nchunksB * NR, 256, 0, stream>>>(gbase, p_src, p_dst, gbase2, p2);

  subscatter_kernel<<<NSB, 512, 0, stream>>>(gbase2, p2, row_ptr, csr_src);

  aggr_kernel<<<(N + 3) / 4, 256, 0, stream>>>(h, row_ptr, csr_src, aggr, N);
  gemm_kernel<<<mgrid, 256, 0, stream>>>(aggr, h, W1l, b1l, W1r, h, N);

  aggr_kernel<<<(N + 3) / 4, 256, 0, stream>>>(h, row_ptr, csr_src, aggr, N);
  gemm_cls_kernel<<<mgrid, 256, 0, stream>>>(aggr, h, W2l, b2l, W2r, Wc, bc, out, N);
}

// Round 6
// 679.700 us; speedup vs baseline: 1.8016x; 1.1445x over previous
//
#include <hip/hip_runtime.h>
#include <hip/hip_bf16.h>

// GraphSAGE forward: proj -> [aggr -> gemm] x2 (+cls fused into gemm2)
// N=200000, E=3200000, IN_DIM=165, HID=64.
//
// R14 design notes:
//  - post-mortem R13: CSR build clean; bottleneck is now the aggregation
//    gather itself: 819MB/pass logical (256B/edge random rows), 383MB L2
//    misses at 3.8TB/s, 117us x2. Random src over a 51.2MB h -> cache
//    capacity limit; the direct lever is bytes/row.
//  - h stored in BF16 (RNE). Gather + gemm lin_r operand read bf16;
//    ALL accumulation, aggr tensor, weights, x stay fp32.
//    Gather traffic halves (410MB logical) and halved footprint raises L2
//    hit rate. hb (25.6MB) replaces h (51.2MB): workspace ~90MB.
//  - aggr restructured: 8-lane groups, ushort8 (16B) row loads, 2-deep
//    unroll; reduce over grp via shfl_xor 8/16/32.
//  - gemm staging vectorized: f4 x2 (aggr) + ushort8 (h) per thread
//    (was scalar fp32 loads).
//  - CSR build (bucket->subsplit->subscatter) unchanged from R13.

#define NNODES 200000
#define NEDGES 3200000
#define INDIM 165
#define HID 64

#define NR 8
#define RSIZE (NNODES / NR)   // 25000
#define CAP 416000            // per-bucket capacity (phase A)
#define NSUB 25               // sub-buckets per bucket
#define SUBSZ 1000            // nodes per sub-bucket
#define NSB (NR * NSUB)       // 200
#define CAP2 20480            // per-sub-bucket capacity
#define ACHUNK 4096

#define BKP 15            // proj K chunk: 165 = 11*15
#define BKG 16            // gemm K chunk: 64 = 4*16
#define NPB 128           // nodes per matmul block
#define XSTR 132          // 128 + 4 pad

typedef float f4 __attribute__((ext_vector_type(4)));
typedef unsigned short u16;
typedef u16 us8 __attribute__((ext_vector_type(8)));

__device__ __forceinline__ u16 f2bf(float f) {
  unsigned u = __float_as_uint(f);
  return (u16)((u + 0x7FFFu + ((u >> 16) & 1u)) >> 16);   // RNE
}
__device__ __forceinline__ float bf2f(u16 v) {
  return __uint_as_float((unsigned)v << 16);
}

#define RELU4(v) { v.x=fmaxf(v.x,0.f); v.y=fmaxf(v.y,0.f); v.z=fmaxf(v.z,0.f); v.w=fmaxf(v.w,0.f); }

#define MT_FMA1(xv, wv0, wv1) \
  accA[0] += xv.x * wv0; accB[0] += xv.x * wv1; \
  accA[1] += xv.y * wv0; accB[1] += xv.y * wv1; \
  accA[2] += xv.z * wv0; accB[2] += xv.z * wv1; \
  accA[3] += xv.w * wv0; accB[3] += xv.w * wv1;

#define ACC8(v, lo, hi) { \
  lo.x += bf2f(v[0]); lo.y += bf2f(v[1]); lo.z += bf2f(v[2]); lo.w += bf2f(v[3]); \
  hi.x += bf2f(v[4]); hi.y += bf2f(v[5]); hi.z += bf2f(v[6]); hi.w += bf2f(v[7]); }

// ---------------- proj: hb = bf16(relu(x @ Wp + bp)) ----------------------
__global__ __launch_bounds__(256, 4)
void proj_kernel(const float* __restrict__ x,
                 const float* __restrict__ Wp,
                 const float* __restrict__ bp,
                 u16* __restrict__ hb, int n) {
  __shared__ float x_s[BKP * XSTR];
  __shared__ float w_s[BKP * HID];
  int t = threadIdx.x;
  int tx = t & 7;
  int ng = t >> 3;
  int n0 = blockIdx.x * NPB;

  f4 b0 = ((const f4*)bp)[tx * 2];
  f4 b1 = ((const f4*)bp)[tx * 2 + 1];
  f4 accA[4], accB[4];
  #pragma unroll
  for (int i = 0; i < 4; ++i) { accA[i] = b0; accB[i] = b1; }

  for (int kc = 0; kc < INDIM / BKP; ++kc) {
    for (int i = t; i < NPB * BKP; i += 256) {
      int node = i / BKP, col = i - node * BKP;
      int gi = n0 + node; if (gi >= n) gi = n - 1;
      x_s[col * XSTR + node] = x[(size_t)gi * INDIM + kc * BKP + col];
    }
    if (t < BKP * HID / 4)
      ((f4*)w_s)[t] = ((const f4*)(Wp + kc * BKP * HID))[t];
    __syncthreads();
    #pragma unroll
    for (int k = 0; k < BKP; ++k) {
      f4 xv = *(const f4*)&x_s[k * XSTR + ng * 4];
      f4 wv0 = *(const f4*)&w_s[k * HID + tx * 8];
      f4 wv1 = *(const f4*)&w_s[k * HID + tx * 8 + 4];
      MT_FMA1(xv, wv0, wv1)
    }
    __syncthreads();
  }
  #pragma unroll
  for (int i = 0; i < 4; ++i) {
    int node = n0 + ng * 4 + i;
    if (node < n) {
      f4 a = accA[i], b = accB[i];
      RELU4(a) RELU4(b)
      us8 o;
      o[0]=f2bf(a.x); o[1]=f2bf(a.y); o[2]=f2bf(a.z); o[3]=f2bf(a.w);
      o[4]=f2bf(b.x); o[5]=f2bf(b.y); o[6]=f2bf(b.z); o[7]=f2bf(b.w);
      *(us8*)&hb[(size_t)node * HID + tx * 8] = o;
    }
  }
}

// ---------------- phase A: bucket edges by dst range ----------------------
__global__ __launch_bounds__(256)
void bucket_kernel(const int* __restrict__ src, const int* __restrict__ dst,
                   int* __restrict__ gbase,
                   int* __restrict__ p_src, int* __restrict__ p_dst, int e) {
  __shared__ int wpart[4][NR];
  __shared__ int wbase[4][NR];
  __shared__ int bbase[NR];
  __shared__ int posm[NR][256];
  int t = threadIdx.x;
  int lane = t & 63, wid = t >> 6;
  int base = blockIdx.x * ACHUNK;

  int dreg[16];
  int c[NR];
  #pragma unroll
  for (int r = 0; r < NR; ++r) c[r] = 0;
  #pragma unroll
  for (int j = 0; j < 16; ++j) {
    int i = base + t + j * 256;
    int d = (i < e) ? __builtin_nontemporal_load(&dst[i]) : -1;
    dreg[j] = d;
    if (d >= 0) c[d / RSIZE]++;
  }
  int excl[NR];
  #pragma unroll
  for (int r = 0; r < NR; ++r) {
    int v = c[r];
    int incl = v;
    #pragma unroll
    for (int off = 1; off < 64; off <<= 1) {
      int y = __shfl_up(incl, off, 64);
      if (lane >= off) incl += y;
    }
    excl[r] = incl - v;
    if (lane == 63) wpart[wid][r] = incl;
  }
  __syncthreads();
  if (t < NR) {
    int s0 = wpart[0][t], s1 = wpart[1][t], s2 = wpart[2][t], s3 = wpart[3][t];
    int tot = s0 + s1 + s2 + s3;
    bbase[t] = atomicAdd(&gbase[t], tot);
    wbase[0][t] = 0; wbase[1][t] = s0; wbase[2][t] = s0 + s1; wbase[3][t] = s0 + s1 + s2;
  }
  __syncthreads();
  #pragma unroll
  for (int r = 0; r < NR; ++r)
    posm[r][t] = r * CAP + bbase[r] + wbase[wid][r] + excl[r];
  #pragma unroll
  for (int j = 0; j < 16; ++j) {
    int d = dreg[j];
    if (d >= 0) {
      int s = __builtin_nontemporal_load(&src[base + t + j * 256]);
      int r = d / RSIZE;
      int p = posm[r][t]++;
      p_dst[p] = d;
      p_src[p] = s;
    }
  }
}

// ---------------- phase A2: split each bucket into 25 sub-buckets ---------
__global__ __launch_bounds__(256)
void subsplit_kernel(const int* __restrict__ gbase,
                     const int* __restrict__ p_src, const int* __restrict__ p_dst,
                     int* __restrict__ gbase2, unsigned int* __restrict__ p2) {
  __shared__ int wpart[4][NSUB];
  __shared__ int wbase[4][NSUB];
  __shared__ int bbase[NSUB];
  __shared__ int posm[NSUB][256];
  int r = blockIdx.x & (NR - 1);
  int chunk = blockIdx.x >> 3;
  int n_r = gbase[r];
  int base = chunk * ACHUNK;
  if (base >= n_r) return;
  int end = min(base + ACHUNK, n_r);
  int t = threadIdx.x;
  int lane = t & 63, wid = t >> 6;
  const int* pd = p_dst + (size_t)r * CAP;
  const int* ps = p_src + (size_t)r * CAP;

  int dreg[16];
  int c[NSUB];
  #pragma unroll
  for (int s2 = 0; s2 < NSUB; ++s2) c[s2] = 0;
  #pragma unroll
  for (int j = 0; j < 16; ++j) {
    int i = base + t + j * 256;
    int d = (i < end) ? __builtin_nontemporal_load(&pd[i]) : -1;
    dreg[j] = d;
    int sub = (d >= 0) ? (unsigned)(d - r * RSIZE) / SUBSZ : -1;
    #pragma unroll
    for (int s2 = 0; s2 < NSUB; ++s2) c[s2] += (sub == s2);
  }
  int excl[NSUB];
  #pragma unroll
  for (int s2 = 0; s2 < NSUB; ++s2) {
    int v = c[s2];
    int incl = v;
    #pragma unroll
    for (int off = 1; off < 64; off <<= 1) {
      int y = __shfl_up(incl, off, 64);
      if (lane >= off) incl += y;
    }
    excl[s2] = incl - v;
    if (lane == 63) wpart[wid][s2] = incl;
  }
  __syncthreads();
  for (int s2 = t; s2 < NSUB; s2 += 256) {
    int s0 = wpart[0][s2], s1 = wpart[1][s2], sB = wpart[2][s2], sC = wpart[3][s2];
    int tot = s0 + s1 + sB + sC;
    bbase[s2] = atomicAdd(&gbase2[r * NSUB + s2], tot);
    wbase[0][s2] = 0; wbase[1][s2] = s0; wbase[2][s2] = s0 + s1; wbase[3][s2] = s0 + s1 + sB;
  }
  __syncthreads();
  #pragma unroll
  for (int s2 = 0; s2 < NSUB; ++s2)
    posm[s2][t] = (r * NSUB + s2) * CAP2 + bbase[s2] + wbase[wid][s2] + excl[s2];
  #pragma unroll
  for (int j = 0; j < 16; ++j) {
    int d = dreg[j];
    if (d >= 0) {
      int i = base + t + j * 256;
      int s = __builtin_nontemporal_load(&ps[i]);
      int dl0 = d - r * RSIZE;
      int sub = (unsigned)dl0 / SUBSZ;
      int dlocal = dl0 - sub * SUBSZ;
      int p = posm[sub][t]++;
      p2[p] = ((unsigned)dlocal << 18) | (unsigned)s;
    }
  }
}

// ---------------- phase B: subscatter (hist+scan+scatter, all LDS) --------
__global__ __launch_bounds__(512)
void subscatter_kernel(const int* __restrict__ gbase2,
                       const unsigned int* __restrict__ p2,
                       int* __restrict__ row_ptr,
                       int* __restrict__ csr_src) {
  __shared__ int hist[SUBSZ];
  __shared__ int sc[256];
  __shared__ int wsum[8];
  int sb = blockIdx.x;
  int t = threadIdx.x;
  int lane = t & 63, wid = t >> 6;

  if (t < 256) sc[t] = (t < NSB) ? gbase2[t] : 0;
  __syncthreads();
  for (int off = 1; off < 256; off <<= 1) {
    int y = 0;
    if (t < 256 && t >= off) y = sc[t - off];
    __syncthreads();
    if (t < 256) sc[t] += y;
    __syncthreads();
  }
  int n = gbase2[sb];
  int base0 = sc[sb] - n;

  for (int i = t; i < SUBSZ; i += 512) hist[i] = 0;
  __syncthreads();

  const unsigned int* pl = p2 + (size_t)sb * CAP2;
  for (int i = t; i < n; i += 512)
    atomicAdd(&hist[pl[i] >> 18], 1);
  __syncthreads();

  int e0 = t * 2, e1 = e0 + 1;
  int v0 = (e0 < SUBSZ) ? hist[e0] : 0;
  int v1 = (e1 < SUBSZ) ? hist[e1] : 0;
  int s = v0 + v1;
  int incl = s;
  #pragma unroll
  for (int off = 1; off < 64; off <<= 1) {
    int y = __shfl_up(incl, off, 64);
    if (lane >= off) incl += y;
  }
  if (lane == 63) wsum[wid] = incl;
  __syncthreads();
  if (t == 0) {
    int run = 0;
    #pragma unroll
    for (int w = 0; w < 8; ++w) { int v = wsum[w]; wsum[w] = run; run += v; }
  }
  __syncthreads();
  int b0 = base0 + (incl - s) + wsum[wid];
  int dst0 = sb * SUBSZ;
  if (e0 < SUBSZ) { hist[e0] = b0;      row_ptr[dst0 + e0] = b0; }
  if (e1 < SUBSZ) { hist[e1] = b0 + v0; row_ptr[dst0 + e1] = b0 + v0; }
  if (sb == NSB - 1 && t == 0) row_ptr[NNODES] = NEDGES;
  __syncthreads();

  for (int i = t; i < n; i += 512) {
    unsigned int w = pl[i];
    int dl = (int)(w >> 18);
    int srcv = (int)(w & 0x3FFFFu);
    int pos = atomicAdd(&hist[dl], 1);
    csr_src[pos] = srcv;
  }
}

// ---------------- mean aggregation (pull, CSR, bf16 gather) ---------------
__global__ __launch_bounds__(256)
void aggr_kernel(const u16* __restrict__ hb,
                 const int* __restrict__ row_ptr,
                 const int* __restrict__ csr_src,
                 float* __restrict__ aggr, int n) {
  int lane = threadIdx.x & 63;
  int grp = lane >> 3, sub = lane & 7;       // 8 groups x 8 col-lanes
  int node = (blockIdx.x * blockDim.x + threadIdx.x) >> 6;
  if (node >= n) return;
  int r0 = row_ptr[node], r1 = row_ptr[node + 1];
  f4 a0 = {0.f,0.f,0.f,0.f}, a1 = {0.f,0.f,0.f,0.f};
  f4 b0 = {0.f,0.f,0.f,0.f}, b1 = {0.f,0.f,0.f,0.f};
  int p = r0;
  for (; p + 16 <= r1; p += 16) {
    int i0 = csr_src[p + grp];
    int i1 = csr_src[p + 8 + grp];
    us8 v0 = *(const us8*)(hb + (size_t)i0 * HID + sub * 8);
    us8 v1 = *(const us8*)(hb + (size_t)i1 * HID + sub * 8);
    ACC8(v0, a0, a1)
    ACC8(v1, b0, b1)
  }
  if (p + 8 <= r1) {
    int i0 = csr_src[p + grp];
    us8 v0 = *(const us8*)(hb + (size_t)i0 * HID + sub * 8);
    ACC8(v0, a0, a1)
    p += 8;
  }
  if (grp < r1 - p) {
    int i0 = csr_src[p + grp];
    us8 v0 = *(const us8*)(hb + (size_t)i0 * HID + sub * 8);
    ACC8(v0, b0, b1)
  }
  a0 += b0; a1 += b1;
  #pragma unroll
  for (int c = 0; c < 4; ++c) {
    float v = a0[c];
    v += __shfl_xor(v, 8, 64); v += __shfl_xor(v, 16, 64); v += __shfl_xor(v, 32, 64);
    a0[c] = v;
    float w = a1[c];
    w += __shfl_xor(w, 8, 64); w += __shfl_xor(w, 16, 64); w += __shfl_xor(w, 32, 64);
    a1[c] = w;
  }
  if (grp == 0) {
    int deg = r1 - r0;
    float rdeg = 1.f / (float)(deg > 1 ? deg : 1);
    *(f4*)(aggr + (size_t)node * HID + sub * 8)     = a0 * rdeg;
    *(f4*)(aggr + (size_t)node * HID + sub * 8 + 4) = a1 * rdeg;
  }
}

// ---------------- gemm: relu(aggr@Wl + bl + h@Wr) [+cls] ------------------
// staging: per thread 2x f4 (aggr) + 1x ushort8 (h bf16), converted to f32
// in LDS. compute identical to R10.
#define GEMM_BODY(aggrp, hbp) \
  { \
    int snode = t >> 1, k0 = (t & 1) * 8; \
    int gi = n0 + snode; if (gi >= n) gi = n - 1; \
    const float* ap = aggrp + (size_t)gi * HID + k0; \
    const u16*   hp = hbp   + (size_t)gi * HID + k0; \
    for (int kc = 0; kc < HID / BKG; ++kc) { \
      f4 av0 = *(const f4*)(ap + kc * BKG); \
      f4 av1 = *(const f4*)(ap + kc * BKG + 4); \
      us8 hv = *(const us8*)(hp + kc * BKG); \
      float* as = &a_s[k0 * XSTR + snode]; \
      float* hs = &h_s[k0 * XSTR + snode]; \
      as[0*XSTR]=av0.x; as[1*XSTR]=av0.y; as[2*XSTR]=av0.z; as[3*XSTR]=av0.w; \
      as[4*XSTR]=av1.x; as[5*XSTR]=av1.y; as[6*XSTR]=av1.z; as[7*XSTR]=av1.w; \
      hs[0*XSTR]=bf2f(hv[0]); hs[1*XSTR]=bf2f(hv[1]); hs[2*XSTR]=bf2f(hv[2]); hs[3*XSTR]=bf2f(hv[3]); \
      hs[4*XSTR]=bf2f(hv[4]); hs[5*XSTR]=bf2f(hv[5]); hs[6*XSTR]=bf2f(hv[6]); hs[7*XSTR]=bf2f(hv[7]); \
      ((f4*)wl_s)[t] = ((const f4*)(Wl + kc * BKG * HID))[t]; \
      ((f4*)wr_s)[t] = ((const f4*)(Wr + kc * BKG * HID))[t]; \
      __syncthreads(); \
      _Pragma("unroll") \
      for (int k = 0; k < BKG; ++k) { \
        f4 av = *(const f4*)&a_s[k * XSTR + ng * 4]; \
        f4 hv2 = *(const f4*)&h_s[k * XSTR + ng * 4]; \
        f4 wl0 = *(const f4*)&wl_s[k * HID + tx * 8]; \
        f4 wl1 = *(const f4*)&wl_s[k * HID + tx * 8 + 4]; \
        f4 wr0 = *(const f4*)&wr_s[k * HID + tx * 8]; \
        f4 wr1 = *(const f4*)&wr_s[k * HID + tx * 8 + 4]; \
        accA[0] += av.x * wl0 + hv2.x * wr0;  accB[0] += av.x * wl1 + hv2.x * wr1; \
        accA[1] += av.y * wl0 + hv2.y * wr0;  accB[1] += av.y * wl1 + hv2.y * wr1; \
        accA[2] += av.z * wl0 + hv2.z * wr0;  accB[2] += av.z * wl1 + hv2.z * wr1; \
        accA[3] += av.w * wl0 + hv2.w * wr0;  accB[3] += av.w * wl1 + hv2.w * wr1; \
      } \
      __syncthreads(); \
    } \
  }

__global__ __launch_bounds__(256, 4)
void gemm_kernel(const float* __restrict__ aggr,
                 const u16* __restrict__ hbin,
                 const float* __restrict__ Wl, const float* __restrict__ bl,
                 const float* __restrict__ Wr,
                 u16* __restrict__ hbout, int n) {
  __shared__ float a_s[BKG * XSTR];
  __shared__ float h_s[BKG * XSTR];
  __shared__ float wl_s[BKG * HID];
  __shared__ float wr_s[BKG * HID];
  int t = threadIdx.x;
  int tx = t & 7;
  int ng = t >> 3;
  int n0 = blockIdx.x * NPB;

  f4 b0 = ((const f4*)bl)[tx * 2];
  f4 b1 = ((const f4*)bl)[tx * 2 + 1];
  f4 accA[4], accB[4];
  #pragma unroll
  for (int i = 0; i < 4; ++i) { accA[i] = b0; accB[i] = b1; }

  GEMM_BODY(aggr, hbin)

  #pragma unroll
  for (int i = 0; i < 4; ++i) {
    int node = n0 + ng * 4 + i;
    if (node < n) {
      f4 a = accA[i], b = accB[i];
      RELU4(a) RELU4(b)
      us8 o;
      o[0]=f2bf(a.x); o[1]=f2bf(a.y); o[2]=f2bf(a.z); o[3]=f2bf(a.w);
      o[4]=f2bf(b.x); o[5]=f2bf(b.y); o[6]=f2bf(b.z); o[7]=f2bf(b.w);
      *(us8*)&hbout[(size_t)node * HID + tx * 8] = o;
    }
  }
}

__global__ __launch_bounds__(256, 4)
void gemm_cls_kernel(const float* __restrict__ aggr,
                     const u16* __restrict__ hbin,
                     const float* __restrict__ Wl, const float* __restrict__ bl,
                     const float* __restrict__ Wr,
                     const float* __restrict__ Wc, const float* __restrict__ bc,
                     float* __restrict__ out, int n) {
  __shared__ float a_s[BKG * XSTR];
  __shared__ float h_s[BKG * XSTR];
  __shared__ float wl_s[BKG * HID];
  __shared__ float wr_s[BKG * HID];
  int t = threadIdx.x;
  int tx = t & 7;
  int ng = t >> 3;
  int n0 = blockIdx.x * NPB;

  f4 b0 = ((const f4*)bl)[tx * 2];
  f4 b1 = ((const f4*)bl)[tx * 2 + 1];
  f4 accA[4], accB[4];
  #pragma unroll
  for (int i = 0; i < 4; ++i) { accA[i] = b0; accB[i] = b1; }

  GEMM_BODY(aggr, hbin)

  f4 wc0 = ((const f4*)Wc)[tx * 2];
  f4 wc1 = ((const f4*)Wc)[tx * 2 + 1];
  float bcv = bc[0];
  #pragma unroll
  for (int i = 0; i < 4; ++i) {
    f4 a = accA[i], b = accB[i];
    RELU4(a) RELU4(b)
    float s = a.x * wc0.x + a.y * wc0.y + a.z * wc0.z + a.w * wc0.w
            + b.x * wc1.x + b.y * wc1.y + b.z * wc1.z + b.w * wc1.w;
    s += __shfl_xor(s, 1, 64);
    s += __shfl_xor(s, 2, 64);
    s += __shfl_xor(s, 4, 64);
    int node = n0 + ng * 4 + i;
    if (tx == 0 && node < n) out[node] = s + bcv;
  }
}

extern "C" void kernel_launch(void* const* d_in, const int* in_sizes, int n_in,
                              void* d_out, int out_size, void* d_ws, size_t ws_size,
                              hipStream_t stream) {
  const float* x   = (const float*)d_in[0];
  const int*   ei  = (const int*)d_in[1];
  const float* Wp  = (const float*)d_in[2];
  const float* bp  = (const float*)d_in[3];
  const float* W1l = (const float*)d_in[4];
  const float* b1l = (const float*)d_in[5];
  const float* W1r = (const float*)d_in[6];
  const float* W2l = (const float*)d_in[7];
  const float* b2l = (const float*)d_in[8];
  const float* W2r = (const float*)d_in[9];
  const float* Wc  = (const float*)d_in[10];
  const float* bc  = (const float*)d_in[11];
  float* out = (float*)d_out;

  const int N = NNODES, E = NEDGES;
  const int* src = ei;
  const int* dst = ei + E;

  char* ws = (char*)d_ws;
  u16*   hb      = (u16*)  (ws + 0);           // 25,600,000 B
  float* aggr    = (float*)(ws + 25600000);    // 51,200,000 B -> 76,800,000
  // aliases inside aggr region (dead before aggr_kernel writes):
  int*   p_src   = (int*)  (ws + 25600000);    // 13,312,000
  int*   p_dst   = p_src + (size_t)NR * CAP;   // +13,312,000 -> 52,224,000
  unsigned int* p2 = (unsigned int*)(ws + 52224000); // 16,384,000 -> 68,608,000
  int*   gbase   = (int*)  (ws + 76800000);    // 32 B
  int*   gbase2  = (int*)  (ws + 76800032);    // 800 B
  int*   row_ptr = (int*)  (ws + 76800832);    // 800,004 B
  int*   csr_src = (int*)  (ws + 77600896);    // 12,800,000 B -> 90,400,896

  hipMemsetAsync(gbase, 0, 832, stream);

  int mgrid = (N + NPB - 1) / NPB;                     // 1563
  proj_kernel<<<mgrid, 256, 0, stream>>>(x, Wp, bp, hb, N);

  int nchunksA = (E + ACHUNK - 1) / ACHUNK;            // 782
  bucket_kernel<<<nchunksA, 256, 0, stream>>>(src, dst, gbase, p_src, p_dst, E);

  int nchunksB = (CAP + ACHUNK - 1) / ACHUNK;          // 102
  subsplit_kernel<<<nchunksB * NR, 256, 0, stream>>>(gbase, p_src, p_dst, gbase2, p2);

  subscatter_kernel<<<NSB, 512, 0, stream>>>(gbase2, p2, row_ptr, csr_src);

  aggr_kernel<<<(N + 3) / 4, 256, 0, stream>>>(hb, row_ptr, csr_src, aggr, N);
  gemm_kernel<<<mgrid, 256, 0, stream>>>(aggr, hb, W1l, b1l, W1r, hb, N);

  aggr_kernel<<<(N + 3) / 4, 256, 0, stream>>>(hb, row_ptr, csr_src, aggr, N);
  gemm_cls_kernel<<<mgrid, 256, 0, stream>>>(aggr, hb, W2l, b2l, W2r, Wc, bc, out, N);
}

// Round 7
// 662.415 us; speedup vs baseline: 1.8486x; 1.0261x over previous
//
#include <hip/hip_runtime.h>
#include <hip/hip_bf16.h>

// GraphSAGE forward: proj -> [aggr -> gemm] x2 (+cls fused into gemm2)
// N=200000, E=3200000, IN_DIM=165, HID=64.
//
// R15 design notes:
//  - post-mortem R14: bf16-h halved gather traffic (aggr off top-5).
//    proj now leads: 107us vs 27us compute / 24us BW floors, VALU 41%,
//    HBM 21% -> latency-serialized phases (1920 scalar x-loads drain at
//    each of 11 barriers).
//  - fix: register double-buffered staging (T14) for proj AND gemms.
//    R9's version spilled because gemm staged 64 scalar regs on 64 acc;
//    now proj = 8 regs on 32 acc (~56 VGPR), gemm = 20 regs on 32 acc
//    (~60 VGPR) -- both far under the 128/wave budget of (256,4).
//  - everything else unchanged from R14 (bucket->subsplit->subscatter CSR
//    build; bf16 h tensor; fp32 accum everywhere).

#define NNODES 200000
#define NEDGES 3200000
#define INDIM 165
#define HID 64

#define NR 8
#define RSIZE (NNODES / NR)   // 25000
#define CAP 416000            // per-bucket capacity (phase A)
#define NSUB 25               // sub-buckets per bucket
#define SUBSZ 1000            // nodes per sub-bucket
#define NSB (NR * NSUB)       // 200
#define CAP2 20480            // per-sub-bucket capacity
#define ACHUNK 4096

#define BKP 15            // proj K chunk: 165 = 11*15
#define BKG 16            // gemm K chunk: 64 = 4*16
#define NPB 128           // nodes per matmul block
#define XSTR 132          // 128 + 4 pad

typedef float f4 __attribute__((ext_vector_type(4)));
typedef unsigned short u16;
typedef u16 us8 __attribute__((ext_vector_type(8)));

__device__ __forceinline__ u16 f2bf(float f) {
  unsigned u = __float_as_uint(f);
  return (u16)((u + 0x7FFFu + ((u >> 16) & 1u)) >> 16);   // RNE
}
__device__ __forceinline__ float bf2f(u16 v) {
  return __uint_as_float((unsigned)v << 16);
}

#define RELU4(v) { v.x=fmaxf(v.x,0.f); v.y=fmaxf(v.y,0.f); v.z=fmaxf(v.z,0.f); v.w=fmaxf(v.w,0.f); }

#define MT_FMA1(xv, wv0, wv1) \
  accA[0] += xv.x * wv0; accB[0] += xv.x * wv1; \
  accA[1] += xv.y * wv0; accB[1] += xv.y * wv1; \
  accA[2] += xv.z * wv0; accB[2] += xv.z * wv1; \
  accA[3] += xv.w * wv0; accB[3] += xv.w * wv1;

#define ACC8(v, lo, hi) { \
  lo.x += bf2f(v[0]); lo.y += bf2f(v[1]); lo.z += bf2f(v[2]); lo.w += bf2f(v[3]); \
  hi.x += bf2f(v[4]); hi.y += bf2f(v[5]); hi.z += bf2f(v[6]); hi.w += bf2f(v[7]); }

// ---------------- proj: hb = bf16(relu(x @ Wp + bp)) ----------------------
// register double-buffered staging: issue kc+1 loads before computing kc.
__global__ __launch_bounds__(256, 4)
void proj_kernel(const float* __restrict__ x,
                 const float* __restrict__ Wp,
                 const float* __restrict__ bp,
                 u16* __restrict__ hb, int n) {
  __shared__ float x_s[BKP * XSTR];
  __shared__ float w_s[BKP * HID];
  int t = threadIdx.x;
  int tx = t & 7;
  int ng = t >> 3;
  int n0 = blockIdx.x * NPB;

  f4 b0 = ((const f4*)bp)[tx * 2];
  f4 b1 = ((const f4*)bp)[tx * 2 + 1];
  f4 accA[4], accB[4];
  #pragma unroll
  for (int i = 0; i < 4; ++i) { accA[i] = b0; accB[i] = b1; }

  float xr[8];
  f4 wpr;
  // prefetch kc=0
  #pragma unroll
  for (int j = 0; j < 8; ++j) {
    int i = t + j * 256;
    if (i < NPB * BKP) {
      int node = i / BKP, col = i - node * BKP;
      int gi = n0 + node; if (gi >= n) gi = n - 1;
      xr[j] = x[(size_t)gi * INDIM + col];
    }
  }
  if (t < BKP * HID / 4) wpr = ((const f4*)Wp)[t];

  for (int kc = 0; kc < INDIM / BKP; ++kc) {
    if (kc) __syncthreads();            // readers of previous tile done
    #pragma unroll
    for (int j = 0; j < 8; ++j) {
      int i = t + j * 256;
      if (i < NPB * BKP) {
        int node = i / BKP, col = i - node * BKP;
        x_s[col * XSTR + node] = xr[j];
      }
    }
    if (t < BKP * HID / 4) ((f4*)w_s)[t] = wpr;
    __syncthreads();
    if (kc + 1 < INDIM / BKP) {         // issue next-phase loads now;
      #pragma unroll                    // latency hides under the FMAs below
      for (int j = 0; j < 8; ++j) {
        int i = t + j * 256;
        if (i < NPB * BKP) {
          int node = i / BKP, col = i - node * BKP;
          int gi = n0 + node; if (gi >= n) gi = n - 1;
          xr[j] = x[(size_t)gi * INDIM + (kc + 1) * BKP + col];
        }
      }
      if (t < BKP * HID / 4) wpr = ((const f4*)(Wp + (kc + 1) * BKP * HID))[t];
    }
    #pragma unroll
    for (int k = 0; k < BKP; ++k) {
      f4 xv = *(const f4*)&x_s[k * XSTR + ng * 4];
      f4 wv0 = *(const f4*)&w_s[k * HID + tx * 8];
      f4 wv1 = *(const f4*)&w_s[k * HID + tx * 8 + 4];
      MT_FMA1(xv, wv0, wv1)
    }
  }
  #pragma unroll
  for (int i = 0; i < 4; ++i) {
    int node = n0 + ng * 4 + i;
    if (node < n) {
      f4 a = accA[i], b = accB[i];
      RELU4(a) RELU4(b)
      us8 o;
      o[0]=f2bf(a.x); o[1]=f2bf(a.y); o[2]=f2bf(a.z); o[3]=f2bf(a.w);
      o[4]=f2bf(b.x); o[5]=f2bf(b.y); o[6]=f2bf(b.z); o[7]=f2bf(b.w);
      *(us8*)&hb[(size_t)node * HID + tx * 8] = o;
    }
  }
}

// ---------------- phase A: bucket edges by dst range ----------------------
__global__ __launch_bounds__(256)
void bucket_kernel(const int* __restrict__ src, const int* __restrict__ dst,
                   int* __restrict__ gbase,
                   int* __restrict__ p_src, int* __restrict__ p_dst, int e) {
  __shared__ int wpart[4][NR];
  __shared__ int wbase[4][NR];
  __shared__ int bbase[NR];
  __shared__ int posm[NR][256];
  int t = threadIdx.x;
  int lane = t & 63, wid = t >> 6;
  int base = blockIdx.x * ACHUNK;

  int dreg[16];
  int c[NR];
  #pragma unroll
  for (int r = 0; r < NR; ++r) c[r] = 0;
  #pragma unroll
  for (int j = 0; j < 16; ++j) {
    int i = base + t + j * 256;
    int d = (i < e) ? __builtin_nontemporal_load(&dst[i]) : -1;
    dreg[j] = d;
    if (d >= 0) c[d / RSIZE]++;
  }
  int excl[NR];
  #pragma unroll
  for (int r = 0; r < NR; ++r) {
    int v = c[r];
    int incl = v;
    #pragma unroll
    for (int off = 1; off < 64; off <<= 1) {
      int y = __shfl_up(incl, off, 64);
      if (lane >= off) incl += y;
    }
    excl[r] = incl - v;
    if (lane == 63) wpart[wid][r] = incl;
  }
  __syncthreads();
  if (t < NR) {
    int s0 = wpart[0][t], s1 = wpart[1][t], s2 = wpart[2][t], s3 = wpart[3][t];
    int tot = s0 + s1 + s2 + s3;
    bbase[t] = atomicAdd(&gbase[t], tot);
    wbase[0][t] = 0; wbase[1][t] = s0; wbase[2][t] = s0 + s1; wbase[3][t] = s0 + s1 + s2;
  }
  __syncthreads();
  #pragma unroll
  for (int r = 0; r < NR; ++r)
    posm[r][t] = r * CAP + bbase[r] + wbase[wid][r] + excl[r];
  #pragma unroll
  for (int j = 0; j < 16; ++j) {
    int d = dreg[j];
    if (d >= 0) {
      int s = __builtin_nontemporal_load(&src[base + t + j * 256]);
      int r = d / RSIZE;
      int p = posm[r][t]++;
      p_dst[p] = d;
      p_src[p] = s;
    }
  }
}

// ---------------- phase A2: split each bucket into 25 sub-buckets ---------
__global__ __launch_bounds__(256)
void subsplit_kernel(const int* __restrict__ gbase,
                     const int* __restrict__ p_src, const int* __restrict__ p_dst,
                     int* __restrict__ gbase2, unsigned int* __restrict__ p2) {
  __shared__ int wpart[4][NSUB];
  __shared__ int wbase[4][NSUB];
  __shared__ int bbase[NSUB];
  __shared__ int posm[NSUB][256];
  int r = blockIdx.x & (NR - 1);
  int chunk = blockIdx.x >> 3;
  int n_r = gbase[r];
  int base = chunk * ACHUNK;
  if (base >= n_r) return;
  int end = min(base + ACHUNK, n_r);
  int t = threadIdx.x;
  int lane = t & 63, wid = t >> 6;
  const int* pd = p_dst + (size_t)r * CAP;
  const int* ps = p_src + (size_t)r * CAP;

  int dreg[16];
  int c[NSUB];
  #pragma unroll
  for (int s2 = 0; s2 < NSUB; ++s2) c[s2] = 0;
  #pragma unroll
  for (int j = 0; j < 16; ++j) {
    int i = base + t + j * 256;
    int d = (i < end) ? __builtin_nontemporal_load(&pd[i]) : -1;
    dreg[j] = d;
    int sub = (d >= 0) ? (unsigned)(d - r * RSIZE) / SUBSZ : -1;
    #pragma unroll
    for (int s2 = 0; s2 < NSUB; ++s2) c[s2] += (sub == s2);
  }
  int excl[NSUB];
  #pragma unroll
  for (int s2 = 0; s2 < NSUB; ++s2) {
    int v = c[s2];
    int incl = v;
    #pragma unroll
    for (int off = 1; off < 64; off <<= 1) {
      int y = __shfl_up(incl, off, 64);
      if (lane >= off) incl += y;
    }
    excl[s2] = incl - v;
    if (lane == 63) wpart[wid][s2] = incl;
  }
  __syncthreads();
  for (int s2 = t; s2 < NSUB; s2 += 256) {
    int s0 = wpart[0][s2], s1 = wpart[1][s2], sB = wpart[2][s2], sC = wpart[3][s2];
    int tot = s0 + s1 + sB + sC;
    bbase[s2] = atomicAdd(&gbase2[r * NSUB + s2], tot);
    wbase[0][s2] = 0; wbase[1][s2] = s0; wbase[2][s2] = s0 + s1; wbase[3][s2] = s0 + s1 + sB;
  }
  __syncthreads();
  #pragma unroll
  for (int s2 = 0; s2 < NSUB; ++s2)
    posm[s2][t] = (r * NSUB + s2) * CAP2 + bbase[s2] + wbase[wid][s2] + excl[s2];
  #pragma unroll
  for (int j = 0; j < 16; ++j) {
    int d = dreg[j];
    if (d >= 0) {
      int i = base + t + j * 256;
      int s = __builtin_nontemporal_load(&ps[i]);
      int dl0 = d - r * RSIZE;
      int sub = (unsigned)dl0 / SUBSZ;
      int dlocal = dl0 - sub * SUBSZ;
      int p = posm[sub][t]++;
      p2[p] = ((unsigned)dlocal << 18) | (unsigned)s;
    }
  }
}

// ---------------- phase B: subscatter (hist+scan+scatter, all LDS) --------
__global__ __launch_bounds__(512)
void subscatter_kernel(const int* __restrict__ gbase2,
                       const unsigned int* __restrict__ p2,
                       int* __restrict__ row_ptr,
                       int* __restrict__ csr_src) {
  __shared__ int hist[SUBSZ];
  __shared__ int sc[256];
  __shared__ int wsum[8];
  int sb = blockIdx.x;
  int t = threadIdx.x;
  int lane = t & 63, wid = t >> 6;

  if (t < 256) sc[t] = (t < NSB) ? gbase2[t] : 0;
  __syncthreads();
  for (int off = 1; off < 256; off <<= 1) {
    int y = 0;
    if (t < 256 && t >= off) y = sc[t - off];
    __syncthreads();
    if (t < 256) sc[t] += y;
    __syncthreads();
  }
  int n = gbase2[sb];
  int base0 = sc[sb] - n;

  for (int i = t; i < SUBSZ; i += 512) hist[i] = 0;
  __syncthreads();

  const unsigned int* pl = p2 + (size_t)sb * CAP2;
  for (int i = t; i < n; i += 512)
    atomicAdd(&hist[pl[i] >> 18], 1);
  __syncthreads();

  int e0 = t * 2, e1 = e0 + 1;
  int v0 = (e0 < SUBSZ) ? hist[e0] : 0;
  int v1 = (e1 < SUBSZ) ? hist[e1] : 0;
  int s = v0 + v1;
  int incl = s;
  #pragma unroll
  for (int off = 1; off < 64; off <<= 1) {
    int y = __shfl_up(incl, off, 64);
    if (lane >= off) incl += y;
  }
  if (lane == 63) wsum[wid] = incl;
  __syncthreads();
  if (t == 0) {
    int run = 0;
    #pragma unroll
    for (int w = 0; w < 8; ++w) { int v = wsum[w]; wsum[w] = run; run += v; }
  }
  __syncthreads();
  int b0 = base0 + (incl - s) + wsum[wid];
  int dst0 = sb * SUBSZ;
  if (e0 < SUBSZ) { hist[e0] = b0;      row_ptr[dst0 + e0] = b0; }
  if (e1 < SUBSZ) { hist[e1] = b0 + v0; row_ptr[dst0 + e1] = b0 + v0; }
  if (sb == NSB - 1 && t == 0) row_ptr[NNODES] = NEDGES;
  __syncthreads();

  for (int i = t; i < n; i += 512) {
    unsigned int w = pl[i];
    int dl = (int)(w >> 18);
    int srcv = (int)(w & 0x3FFFFu);
    int pos = atomicAdd(&hist[dl], 1);
    csr_src[pos] = srcv;
  }
}

// ---------------- mean aggregation (pull, CSR, bf16 gather) ---------------
__global__ __launch_bounds__(256)
void aggr_kernel(const u16* __restrict__ hb,
                 const int* __restrict__ row_ptr,
                 const int* __restrict__ csr_src,
                 float* __restrict__ aggr, int n) {
  int lane = threadIdx.x & 63;
  int grp = lane >> 3, sub = lane & 7;       // 8 groups x 8 col-lanes
  int node = (blockIdx.x * blockDim.x + threadIdx.x) >> 6;
  if (node >= n) return;
  int r0 = row_ptr[node], r1 = row_ptr[node + 1];
  f4 a0 = {0.f,0.f,0.f,0.f}, a1 = {0.f,0.f,0.f,0.f};
  f4 b0 = {0.f,0.f,0.f,0.f}, b1 = {0.f,0.f,0.f,0.f};
  int p = r0;
  for (; p + 16 <= r1; p += 16) {
    int i0 = csr_src[p + grp];
    int i1 = csr_src[p + 8 + grp];
    us8 v0 = *(const us8*)(hb + (size_t)i0 * HID + sub * 8);
    us8 v1 = *(const us8*)(hb + (size_t)i1 * HID + sub * 8);
    ACC8(v0, a0, a1)
    ACC8(v1, b0, b1)
  }
  if (p + 8 <= r1) {
    int i0 = csr_src[p + grp];
    us8 v0 = *(const us8*)(hb + (size_t)i0 * HID + sub * 8);
    ACC8(v0, a0, a1)
    p += 8;
  }
  if (grp < r1 - p) {
    int i0 = csr_src[p + grp];
    us8 v0 = *(const us8*)(hb + (size_t)i0 * HID + sub * 8);
    ACC8(v0, b0, b1)
  }
  a0 += b0; a1 += b1;
  #pragma unroll
  for (int c = 0; c < 4; ++c) {
    float v = a0[c];
    v += __shfl_xor(v, 8, 64); v += __shfl_xor(v, 16, 64); v += __shfl_xor(v, 32, 64);
    a0[c] = v;
    float w = a1[c];
    w += __shfl_xor(w, 8, 64); w += __shfl_xor(w, 16, 64); w += __shfl_xor(w, 32, 64);
    a1[c] = w;
  }
  if (grp == 0) {
    int deg = r1 - r0;
    float rdeg = 1.f / (float)(deg > 1 ? deg : 1);
    *(f4*)(aggr + (size_t)node * HID + sub * 8)     = a0 * rdeg;
    *(f4*)(aggr + (size_t)node * HID + sub * 8 + 4) = a1 * rdeg;
  }
}

// ---------------- gemm: relu(aggr@Wl + bl + h@Wr) [+cls] ------------------
// register double-buffered staging: per thread 2x f4 (aggr) + us8 (h bf16)
// + 2x f4 (weights), prefetched one kc phase ahead.
#define GEMM_BODY(aggrp, hbp) \
  { \
    int snode = t >> 1, k0 = (t & 1) * 8; \
    int gi = n0 + snode; if (gi >= n) gi = n - 1; \
    const float* ap = aggrp + (size_t)gi * HID + k0; \
    const u16*   hp = hbp   + (size_t)gi * HID + k0; \
    f4 av0 = *(const f4*)(ap); \
    f4 av1 = *(const f4*)(ap + 4); \
    us8 hv = *(const us8*)(hp); \
    f4 wlr = ((const f4*)Wl)[t]; \
    f4 wrr = ((const f4*)Wr)[t]; \
    for (int kc = 0; kc < HID / BKG; ++kc) { \
      if (kc) __syncthreads(); \
      float* as = &a_s[k0 * XSTR + snode]; \
      float* hs = &h_s[k0 * XSTR + snode]; \
      as[0*XSTR]=av0.x; as[1*XSTR]=av0.y; as[2*XSTR]=av0.z; as[3*XSTR]=av0.w; \
      as[4*XSTR]=av1.x; as[5*XSTR]=av1.y; as[6*XSTR]=av1.z; as[7*XSTR]=av1.w; \
      hs[0*XSTR]=bf2f(hv[0]); hs[1*XSTR]=bf2f(hv[1]); hs[2*XSTR]=bf2f(hv[2]); hs[3*XSTR]=bf2f(hv[3]); \
      hs[4*XSTR]=bf2f(hv[4]); hs[5*XSTR]=bf2f(hv[5]); hs[6*XSTR]=bf2f(hv[6]); hs[7*XSTR]=bf2f(hv[7]); \
      ((f4*)wl_s)[t] = wlr; \
      ((f4*)wr_s)[t] = wrr; \
      __syncthreads(); \
      if (kc + 1 < HID / BKG) { \
        av0 = *(const f4*)(ap + (kc + 1) * BKG); \
        av1 = *(const f4*)(ap + (kc + 1) * BKG + 4); \
        hv  = *(const us8*)(hp + (kc + 1) * BKG); \
        wlr = ((const f4*)(Wl + (kc + 1) * BKG * HID))[t]; \
        wrr = ((const f4*)(Wr + (kc + 1) * BKG * HID))[t]; \
      } \
      _Pragma("unroll") \
      for (int k = 0; k < BKG; ++k) { \
        f4 av = *(const f4*)&a_s[k * XSTR + ng * 4]; \
        f4 hv2 = *(const f4*)&h_s[k * XSTR + ng * 4]; \
        f4 wl0 = *(const f4*)&wl_s[k * HID + tx * 8]; \
        f4 wl1 = *(const f4*)&wl_s[k * HID + tx * 8 + 4]; \
        f4 wr0 = *(const f4*)&wr_s[k * HID + tx * 8]; \
        f4 wr1 = *(const f4*)&wr_s[k * HID + tx * 8 + 4]; \
        accA[0] += av.x * wl0 + hv2.x * wr0;  accB[0] += av.x * wl1 + hv2.x * wr1; \
        accA[1] += av.y * wl0 + hv2.y * wr0;  accB[1] += av.y * wl1 + hv2.y * wr1; \
        accA[2] += av.z * wl0 + hv2.z * wr0;  accB[2] += av.z * wl1 + hv2.z * wr1; \
        accA[3] += av.w * wl0 + hv2.w * wr0;  accB[3] += av.w * wl1 + hv2.w * wr1; \
      } \
    } \
  }

__global__ __launch_bounds__(256, 4)
void gemm_kernel(const float* __restrict__ aggr,
                 const u16* __restrict__ hbin,
                 const float* __restrict__ Wl, const float* __restrict__ bl,
                 const float* __restrict__ Wr,
                 u16* __restrict__ hbout, int n) {
  __shared__ float a_s[BKG * XSTR];
  __shared__ float h_s[BKG * XSTR];
  __shared__ float wl_s[BKG * HID];
  __shared__ float wr_s[BKG * HID];
  int t = threadIdx.x;
  int tx = t & 7;
  int ng = t >> 3;
  int n0 = blockIdx.x * NPB;

  f4 b0 = ((const f4*)bl)[tx * 2];
  f4 b1 = ((const f4*)bl)[tx * 2 + 1];
  f4 accA[4], accB[4];
  #pragma unroll
  for (int i = 0; i < 4; ++i) { accA[i] = b0; accB[i] = b1; }

  GEMM_BODY(aggr, hbin)

  #pragma unroll
  for (int i = 0; i < 4; ++i) {
    int node = n0 + ng * 4 + i;
    if (node < n) {
      f4 a = accA[i], b = accB[i];
      RELU4(a) RELU4(b)
      us8 o;
      o[0]=f2bf(a.x); o[1]=f2bf(a.y); o[2]=f2bf(a.z); o[3]=f2bf(a.w);
      o[4]=f2bf(b.x); o[5]=f2bf(b.y); o[6]=f2bf(b.z); o[7]=f2bf(b.w);
      *(us8*)&hbout[(size_t)node * HID + tx * 8] = o;
    }
  }
}

__global__ __launch_bounds__(256, 4)
void gemm_cls_kernel(const float* __restrict__ aggr,
                     const u16* __restrict__ hbin,
                     const float* __restrict__ Wl, const float* __restrict__ bl,
                     const float* __restrict__ Wr,
                     const float* __restrict__ Wc, const float* __restrict__ bc,
                     float* __restrict__ out, int n) {
  __shared__ float a_s[BKG * XSTR];
  __shared__ float h_s[BKG * XSTR];
  __shared__ float wl_s[BKG * HID];
  __shared__ float wr_s[BKG * HID];
  int t = threadIdx.x;
  int tx = t & 7;
  int ng = t >> 3;
  int n0 = blockIdx.x * NPB;

  f4 b0 = ((const f4*)bl)[tx * 2];
  f4 b1 = ((const f4*)bl)[tx * 2 + 1];
  f4 accA[4], accB[4];
  #pragma unroll
  for (int i = 0; i < 4; ++i) { accA[i] = b0; accB[i] = b1; }

  GEMM_BODY(aggr, hbin)

  f4 wc0 = ((const f4*)Wc)[tx * 2];
  f4 wc1 = ((const f4*)Wc)[tx * 2 + 1];
  float bcv = bc[0];
  #pragma unroll
  for (int i = 0; i < 4; ++i) {
    f4 a = accA[i], b = accB[i];
    RELU4(a) RELU4(b)
    float s = a.x * wc0.x + a.y * wc0.y + a.z * wc0.z + a.w * wc0.w
            + b.x * wc1.x + b.y * wc1.y + b.z * wc1.z + b.w * wc1.w;
    s += __shfl_xor(s, 1, 64);
    s += __shfl_xor(s, 2, 64);
    s += __shfl_xor(s, 4, 64);
    int node = n0 + ng * 4 + i;
    if (tx == 0 && node < n) out[node] = s + bcv;
  }
}

extern "C" void kernel_launch(void* const* d_in, const int* in_sizes, int n_in,
                              void* d_out, int out_size, void* d_ws, size_t ws_size,
                              hipStream_t stream) {
  const float* x   = (const float*)d_in[0];
  const int*   ei  = (const int*)d_in[1];
  const float* Wp  = (const float*)d_in[2];
  const float* bp  = (const float*)d_in[3];
  const float* W1l = (const float*)d_in[4];
  const float* b1l = (const float*)d_in[5];
  const float* W1r = (const float*)d_in[6];
  const float* W2l = (const float*)d_in[7];
  const float* b2l = (const float*)d_in[8];
  const float* W2r = (const float*)d_in[9];
  const float* Wc  = (const float*)d_in[10];
  const float* bc  = (const float*)d_in[11];
  float* out = (float*)d_out;

  const int N = NNODES, E = NEDGES;
  const int* src = ei;
  const int* dst = ei + E;

  char* ws = (char*)d_ws;
  u16*   hb      = (u16*)  (ws + 0);           // 25,600,000 B
  float* aggr    = (float*)(ws + 25600000);    // 51,200,000 B -> 76,800,000
  // aliases inside aggr region (dead before aggr_kernel writes):
  int*   p_src   = (int*)  (ws + 25600000);    // 13,312,000
  int*   p_dst   = p_src + (size_t)NR * CAP;   // +13,312,000 -> 52,224,000
  unsigned int* p2 = (unsigned int*)(ws + 52224000); // 16,384,000 -> 68,608,000
  int*   gbase   = (int*)  (ws + 76800000);    // 32 B
  int*   gbase2  = (int*)  (ws + 76800032);    // 800 B
  int*   row_ptr = (int*)  (ws + 76800832);    // 800,004 B
  int*   csr_src = (int*)  (ws + 77600896);    // 12,800,000 B -> 90,400,896

  hipMemsetAsync(gbase, 0, 832, stream);

  int mgrid = (N + NPB - 1) / NPB;                     // 1563
  proj_kernel<<<mgrid, 256, 0, stream>>>(x, Wp, bp, hb, N);

  int nchunksA = (E + ACHUNK - 1) / ACHUNK;            // 782
  bucket_kernel<<<nchunksA, 256, 0, stream>>>(src, dst, gbase, p_src, p_dst, E);

  int nchunksB = (CAP + ACHUNK - 1) / ACHUNK;          // 102
  subsplit_kernel<<<nchunksB * NR, 256, 0, stream>>>(gbase, p_src, p_dst, gbase2, p2);

  subscatter_kernel<<<NSB, 512, 0, stream>>>(gbase2, p2, row_ptr, csr_src);

  aggr_kernel<<<(N + 3) / 4, 256, 0, stream>>>(hb, row_ptr, csr_src, aggr, N);
  gemm_kernel<<<mgrid, 256, 0, stream>>>(aggr, hb, W1l, b1l, W1r, hb, N);

  aggr_kernel<<<(N + 3) / 4, 256, 0, stream>>>(hb, row_ptr, csr_src, aggr, N);
  gemm_cls_kernel<<<mgrid, 256, 0, stream>>>(aggr, hb, W2l, b2l, W2r, Wc, bc, out, N);
}